// Round 15
// baseline (537.808 us; speedup 1.0000x reference)
//
#include <hip/hip_runtime.h>
#include <hip/hip_fp16.h>
#include <cstdint>
#include <cstddef>

#define BB 128
#define SS 256
#define LL 10
#define NTAGS 32
#define TAG_START 30
#define TAG_END 31
#define WDIM 100
#define CDIM 30
#define NFILT 30
#define HDIM 100
#define KIN 130      // LSTM_IN = WDIM + FILT
#define KPAD 160     // padded K for f16 GEMM operands
#define GDIM 400     // 4*H
#define NROWS 832    // 13*64 padded W rows
#define NEGV -10000.0f
#define CTOK 8       // tokens per charconv block

// fused-pre block ranges (R25: word branch vectorized)
#define NB_CONV (BB * SS / CTOK)               // 4096
#define NB_WORDA (BB * SS * 12 / 256)          // 1536: uint4 groups d in [0,96)
#define NB_WORDB (BB * SS * 20 / 256)          // 2560: tail d 96..99 + zeros [130,160)
#define NB_WCVT (NROWS * KPAD / 256)           // 520
#define NB_PRE  (NB_CONV + NB_WORDA + NB_WORDB + NB_WCVT)  // 8712

typedef _Float16 h2 __attribute__((ext_vector_type(2)));
typedef _Float16 f16x8 __attribute__((ext_vector_type(8)));
typedef float f32x4 __attribute__((ext_vector_type(4)));

#if __has_builtin(__builtin_amdgcn_fdot2)
#define HAVE_FDOT2 1
#else
#define HAVE_FDOT2 0
#endif

__device__ __forceinline__ float sigm(float x) { return 1.0f / (1.0f + __expf(-x)); }
__device__ __forceinline__ float tanh_fast(float x) { return 2.0f / (1.0f + __expf(-2.0f * x)) - 1.0f; }

// lgkm-only barrier (R15-proven): leaves global prefetch/store in flight.
__device__ __forceinline__ void barrier_lds_only() {
  asm volatile("s_waitcnt lgkmcnt(0)" ::: "memory");
  __builtin_amdgcn_s_barrier();
  asm volatile("" ::: "memory");
}

// ---------------- K1 fused: charconv | word gather | wcvt, by block range ----------------
__global__ __launch_bounds__(256) void k_pre(
    const float* __restrict__ wemb, const int* __restrict__ wx,
    const float* __restrict__ cemb, const float* __restrict__ convw,
    const float* __restrict__ convb, const int* __restrict__ cx,
    const float* __restrict__ wihF, const float* __restrict__ wihB,
    _Float16* __restrict__ x16, _Float16* __restrict__ w16,
    float* __restrict__ out) {
  int blk = blockIdx.x;
  int tid = threadIdx.x;
  if (blk == 0 && tid == 0) out[0] = 0.f;

  if (blk < NB_CONV) {
    int tok8 = tid >> 5;
    int f = tid & 31;
    int token0 = blk * CTOK;
    __shared__ float e[CTOK][LL * CDIM];
    __shared__ float cw[NFILT * 3 * CDIM];   // 2700 floats = 10.8 KB
    __shared__ float cb[NFILT];
    __shared__ int ci[CTOK][LL];
    if (tid < CTOK * LL) {
      int t = tid / LL, l = tid - t * LL;
      ci[t][l] = cx[(token0 + t) * LL + l];
    }
    for (int i = tid; i < NFILT * 3 * CDIM; i += 256) cw[i] = convw[i];
    if (tid < NFILT) cb[tid] = convb[tid];
    __syncthreads();
    for (int i = tid; i < CTOK * LL * CDIM; i += 256) {
      int t = i / (LL * CDIM);
      int r = i - t * (LL * CDIM);
      int l = r / CDIM, c = r - l * CDIM;
      e[t][l * CDIM + c] = cemb[ci[t][l] * CDIM + c];
    }
    __syncthreads();
    if (f < NFILT) {
      float d0[LL], d1[LL], d2[LL];
#pragma unroll
      for (int l = 0; l < LL; l++) { d0[l] = 0.f; d1[l] = 0.f; d2[l] = 0.f; }
      const float* et = &e[tok8][0];
      for (int c = 0; c < CDIM; c++) {
        float w0 = cw[(f * 3 + 0) * CDIM + c];
        float w1 = cw[(f * 3 + 1) * CDIM + c];
        float w2 = cw[(f * 3 + 2) * CDIM + c];
#pragma unroll
        for (int l = 0; l < LL; l++) {
          float ev = et[l * CDIM + c];
          d0[l] += ev * w0; d1[l] += ev * w1; d2[l] += ev * w2;
        }
      }
      float bias = cb[f];
      float m = -3.0e38f;
#pragma unroll
      for (int h = 0; h < LL + 2; h++) {
        float acc = bias;
        int j0 = h - 2, j1 = h - 1, j2 = h;
        if (j0 >= 0 && j0 < LL) acc += d0[j0];
        if (j1 >= 0 && j1 < LL) acc += d1[j1];
        if (j2 >= 0 && j2 < LL) acc += d2[j2];
        m = fmaxf(m, acc);
      }
      x16[(size_t)(token0 + tok8) * KPAD + WDIM + f] = (_Float16)m;
    }
  } else if (blk < NB_CONV + NB_WORDA) {
    // vectorized word gather: one uint4 (8 halves) per thread, d in [0,96)
    int idx = (blk - NB_CONV) * 256 + tid;
    int token = idx / 12;
    int g = idx - token * 12;
    const float* src = wemb + (size_t)wx[token] * WDIM + g * 8;
    float4 f0 = *(const float4*)(src);
    float4 f1 = *(const float4*)(src + 4);
    f16x8 v;
    v[0] = (_Float16)f0.x; v[1] = (_Float16)f0.y;
    v[2] = (_Float16)f0.z; v[3] = (_Float16)f0.w;
    v[4] = (_Float16)f1.x; v[5] = (_Float16)f1.y;
    v[6] = (_Float16)f1.z; v[7] = (_Float16)f1.w;
    *(f16x8*)&x16[(size_t)token * KPAD + g * 8] = v;
  } else if (blk < NB_CONV + NB_WORDA + NB_WORDB) {
    // tail: d 96..99 scalar wemb; zeros for d in [130,160) as uint pairs
    int idx = (blk - NB_CONV - NB_WORDA) * 256 + tid;
    int token = idx / 20;
    int u = idx - token * 20;
    if (u < 4) {
      x16[(size_t)token * KPAD + 96 + u] = (_Float16)wemb[(size_t)wx[token] * WDIM + 96 + u];
    } else if (u < 19) {
      *(uint32_t*)&x16[(size_t)token * KPAD + KIN + 2 * (u - 4)] = 0;
    }
  } else {
    int idx = (blk - NB_CONV - NB_WORDA - NB_WORDB) * 256 + tid;
    int n = idx / KPAD;
    int k = idx - n * KPAD;
    float v = 0.f;
    if (k < KIN && n < 2 * GDIM) {
      v = (n < GDIM) ? wihF[(size_t)n * KIN + k] : wihB[(size_t)(n - GDIM) * KIN + k];
    }
    w16[idx] = (_Float16)v;
  }
}

// ---------------- K2: pre = x @ wih^T + (bih+bhh), MFMA f16 (R25: n-loop-in-block) ----------------
__global__ __launch_bounds__(256) void k_pregemm(
    const _Float16* __restrict__ x16, const _Float16* __restrict__ w16,
    const float* __restrict__ bihF, const float* __restrict__ bhhF,
    const float* __restrict__ bihB, const float* __restrict__ bhhB,
    _Float16* __restrict__ preF, _Float16* __restrict__ preB) {
  __shared__ __align__(16) _Float16 Asl[64 * 168];      // 21.5 KB
  __shared__ __align__(16) _Float16 Bsl[2][64 * 168];   // 43 KB
  int m0 = blockIdx.x * 64;
  int tid = threadIdx.x;
  int lane = tid & 63, w = tid >> 6;
  int quad = lane >> 4, l15 = lane & 15;
  int r = tid >> 2;            // staging row 0..63
  int kk = (tid & 3) * 8;      // k offset within chunk

  const _Float16* xs = x16 + (size_t)(m0 + r) * KPAD + kk;
  const _Float16* ws = w16 + (size_t)r * KPAD + kk;
#pragma unroll
  for (int kc = 0; kc < 5; kc++) {
    *(f16x8*)&Asl[r * 168 + kc * 32 + kk] = *(const f16x8*)(xs + kc * 32);
    *(f16x8*)&Bsl[0][r * 168 + kc * 32 + kk] = *(const f16x8*)(ws + kc * 32);
  }
  __syncthreads();

  for (int nt = 0; nt < 13; nt++) {
    int cur = nt & 1;
    // prefetch next B tile into registers (stays in flight across compute)
    f16x8 nb0, nb1, nb2, nb3, nb4;
    if (nt + 1 < 13) {
      const _Float16* wn = w16 + (size_t)((nt + 1) * 64 + r) * KPAD + kk;
      nb0 = *(const f16x8*)(wn);
      nb1 = *(const f16x8*)(wn + 32);
      nb2 = *(const f16x8*)(wn + 64);
      nb3 = *(const f16x8*)(wn + 96);
      nb4 = *(const f16x8*)(wn + 128);
    }

    f32x4 acc[4];
#pragma unroll
    for (int i = 0; i < 4; i++) acc[i] = (f32x4){0.f, 0.f, 0.f, 0.f};
#pragma unroll
    for (int kc = 0; kc < 5; kc++) {
      f16x8 bfrag = *(const f16x8*)&Bsl[cur][(w * 16 + l15) * 168 + kc * 32 + quad * 8];
#pragma unroll
      for (int mt = 0; mt < 4; mt++) {
        f16x8 afrag = *(const f16x8*)&Asl[(mt * 16 + l15) * 168 + kc * 32 + quad * 8];
        acc[mt] = __builtin_amdgcn_mfma_f32_16x16x32_f16(afrag, bfrag, acc[mt], 0, 0, 0);
      }
    }

    int ng = nt * 64 + w * 16 + l15;  // this lane's output column
    if (ng < 2 * GDIM) {
      int dir = ng >= GDIM;
      int jb = dir ? ng - GDIM : ng;
      _Float16* dst = dir ? preB : preF;
      float bias = (dir ? bihB : bihF)[jb] + (dir ? bhhB : bhhF)[jb];
#pragma unroll
      for (int mt = 0; mt < 4; mt++) {
#pragma unroll
        for (int i = 0; i < 4; i++) {
          int m = m0 + mt * 16 + quad * 4 + i;
          dst[(size_t)m * GDIM + jb] = (_Float16)(acc[mt][i] + bias);
        }
      }
    }

    if (nt + 1 < 13) {
      asm volatile("s_waitcnt vmcnt(0)" ::: "memory");
      int nxt = cur ^ 1;   // buffer last READ in iteration nt-1; all waves past
      *(f16x8*)&Bsl[nxt][r * 168 + 0 * 32 + kk] = nb0;
      *(f16x8*)&Bsl[nxt][r * 168 + 1 * 32 + kk] = nb1;
      *(f16x8*)&Bsl[nxt][r * 168 + 2 * 32 + kk] = nb2;
      *(f16x8*)&Bsl[nxt][r * 168 + 3 * 32 + kk] = nb3;
      *(f16x8*)&Bsl[nxt][r * 168 + 4 * 32 + kk] = nb4;
      __syncthreads();
    }
  }
}

// ---------------- K3: recurrent LSTM scan (R21 fdot2 structure, best measured 164us) ----------------
#define CH 32
#define NCH (SS / CH)
__global__ __launch_bounds__(256, 1) void k_lstm(
    const _Float16* __restrict__ preF, const _Float16* __restrict__ preB,
    const float* __restrict__ whhF, const float* __restrict__ whhB,
    _Float16* __restrict__ hbuf) {
  int blk = blockIdx.x;              // 256 blocks
  int dir = blk >> 7;                // 0 fwd, 1 bwd
  int b = blk & 127;
  const _Float16* pre = dir ? preB : preF;
  const float* whh = dir ? whhB : whhF;
  int tid = threadIdx.x;
  int j = tid >> 1;                  // cell 0..127 (valid < 100)
  int kh = tid & 1;                  // k-half: [0,50) or [50,100)
  bool act = (j < HDIM);
  int jc = act ? j : 0;

  // ---- weight preload: wp[g][q] = whh[g*100+j][kh*50 + 2q .. +1] as half2 ----
  __half2 wp[4][25];
#pragma unroll
  for (int g = 0; g < 4; g++) {
    const float* wr = whh + (size_t)(g * HDIM + jc) * HDIM + kh * 50;
#pragma unroll
    for (int q = 0; q < 25; q++) {
      wp[g][q] = __floats2half2_rn(wr[2 * q], wr[2 * q + 1]);
    }
  }

  // ---- LDS: pre chunk buffer (28.7 KB) + h double buffer (512 B) ----
  __shared__ __align__(16) _Float16 preS[14336];   // 1792 uint4
  __shared__ __align__(16) _Float16 hsh[2][2][64];
  if (tid < 128) ((int*)hsh)[tid] = 0;
  float c = 0.f;

#define GSRC(ck) ((const uint4*)(pre + ((size_t)b * SS + (dir ? (SS - CH - (ck) * CH) : ((ck) * CH))) * GDIM))

  uint4 r0, r1, r2, r3, r4, r5, r6;
  {
    const uint4* s0 = GSRC(0);
    r0 = s0[0 * 256 + tid]; r1 = s0[1 * 256 + tid]; r2 = s0[2 * 256 + tid];
    r3 = s0[3 * 256 + tid]; r4 = s0[4 * 256 + tid]; r5 = s0[5 * 256 + tid];
    r6 = s0[6 * 256 + tid];
  }

  _Float16* hptr = hbuf + ((size_t)b * SS + (dir ? (SS - 1) : 0)) * (2 * HDIM) + dir * HDIM + jc;
  const intptr_t hstep = dir ? -(intptr_t)(2 * HDIM) : (intptr_t)(2 * HDIM);

  int cur = 0;
  for (int ck = 0; ck < NCH; ck++) {
    asm volatile("s_waitcnt vmcnt(0)" ::: "memory");   // staged regs landed
    *(uint4*)&preS[(0 * 256 + tid) * 8] = r0;
    *(uint4*)&preS[(1 * 256 + tid) * 8] = r1;
    *(uint4*)&preS[(2 * 256 + tid) * 8] = r2;
    *(uint4*)&preS[(3 * 256 + tid) * 8] = r3;
    *(uint4*)&preS[(4 * 256 + tid) * 8] = r4;
    *(uint4*)&preS[(5 * 256 + tid) * 8] = r5;
    *(uint4*)&preS[(6 * 256 + tid) * 8] = r6;
    if (ck + 1 < NCH) {
      const uint4* snx = GSRC(ck + 1);
      r0 = snx[0 * 256 + tid]; r1 = snx[1 * 256 + tid]; r2 = snx[2 * 256 + tid];
      r3 = snx[3 * 256 + tid]; r4 = snx[4 * 256 + tid]; r5 = snx[5 * 256 + tid];
      r6 = snx[6 * 256 + tid];
    }
    barrier_lds_only();   // preS (and hsh zeros on ck=0) visible to all waves

    int preOff = (dir ? (CH - 1) * GDIM : 0) + kh * 200 + jc;
    const int pdelta = dir ? -GDIM : GDIM;

    for (int s2 = 0; s2 < CH; s2++) {
      float paF = (float)preS[preOff];
      float pbF = (float)preS[preOff + 100];

      // h of previous step: 50 halves of this lane's k-half (broadcast reads)
      const _Float16* hseg = &hsh[cur][kh][0];
      uint4 hv0 = *(const uint4*)(hseg);
      uint4 hv1 = *(const uint4*)(hseg + 8);
      uint4 hv2 = *(const uint4*)(hseg + 16);
      uint4 hv3 = *(const uint4*)(hseg + 24);
      uint4 hv4 = *(const uint4*)(hseg + 32);
      uint4 hv5 = *(const uint4*)(hseg + 40);
      uint32_t hv6 = *(const uint32_t*)(hseg + 48);
      __half2 hp[25];
      hp[0]  = __builtin_bit_cast(__half2, hv0.x);
      hp[1]  = __builtin_bit_cast(__half2, hv0.y);
      hp[2]  = __builtin_bit_cast(__half2, hv0.z);
      hp[3]  = __builtin_bit_cast(__half2, hv0.w);
      hp[4]  = __builtin_bit_cast(__half2, hv1.x);
      hp[5]  = __builtin_bit_cast(__half2, hv1.y);
      hp[6]  = __builtin_bit_cast(__half2, hv1.z);
      hp[7]  = __builtin_bit_cast(__half2, hv1.w);
      hp[8]  = __builtin_bit_cast(__half2, hv2.x);
      hp[9]  = __builtin_bit_cast(__half2, hv2.y);
      hp[10] = __builtin_bit_cast(__half2, hv2.z);
      hp[11] = __builtin_bit_cast(__half2, hv2.w);
      hp[12] = __builtin_bit_cast(__half2, hv3.x);
      hp[13] = __builtin_bit_cast(__half2, hv3.y);
      hp[14] = __builtin_bit_cast(__half2, hv3.z);
      hp[15] = __builtin_bit_cast(__half2, hv3.w);
      hp[16] = __builtin_bit_cast(__half2, hv4.x);
      hp[17] = __builtin_bit_cast(__half2, hv4.y);
      hp[18] = __builtin_bit_cast(__half2, hv4.z);
      hp[19] = __builtin_bit_cast(__half2, hv4.w);
      hp[20] = __builtin_bit_cast(__half2, hv5.x);
      hp[21] = __builtin_bit_cast(__half2, hv5.y);
      hp[22] = __builtin_bit_cast(__half2, hv5.z);
      hp[23] = __builtin_bit_cast(__half2, hv5.w);
      hp[24] = __builtin_bit_cast(__half2, hv6);

      // 4-gate partial dots over this lane's 50 k values
      float racc[4];
#if HAVE_FDOT2
#pragma unroll
      for (int g = 0; g < 4; g++) {
        float a0 = 0.f, a1 = 0.f;
#pragma unroll
        for (int q = 0; q < 25; q += 2)
          a0 = __builtin_amdgcn_fdot2(__builtin_bit_cast(h2, wp[g][q]),
                                      __builtin_bit_cast(h2, hp[q]), a0, false);
#pragma unroll
        for (int q = 1; q < 25; q += 2)
          a1 = __builtin_amdgcn_fdot2(__builtin_bit_cast(h2, wp[g][q]),
                                      __builtin_bit_cast(h2, hp[q]), a1, false);
        racc[g] = a0 + a1;
      }
#else
      __half2 z = __floats2half2_rn(0.f, 0.f);
#pragma unroll
      for (int g = 0; g < 4; g++) {
        __half2 a0 = z, a1 = z;
#pragma unroll
        for (int q = 0; q < 25; q += 2) a0 = __hfma2(wp[g][q], hp[q], a0);
#pragma unroll
        for (int q = 1; q < 25; q += 2) a1 = __hfma2(wp[g][q], hp[q], a1);
        racc[g] = (__low2float(a0) + __high2float(a0)) +
                  (__low2float(a1) + __high2float(a1));
      }
#endif

      // add pre (each lane of the pair contributes 2 gates), then pair-reduce
      if (kh == 0) { racc[0] += paF; racc[1] += pbF; }
      else         { racc[2] += paF; racc[3] += pbF; }
#pragma unroll
      for (int g = 0; g < 4; g++) racc[g] += __shfl_xor(racc[g], 1);

      // activations (both lanes of the pair compute identically; no divergence)
      float ig = sigm(racc[0]), fg = sigm(racc[1]);
      float g2 = tanh_fast(racc[2]), og = sigm(racc[3]);
      c = fg * c + ig * g2;
      float h = og * tanh_fast(c);

      if (act && kh == 0) {
        int seg = (j >= 50) ? 1 : 0;
        hsh[cur ^ 1][seg][j - seg * 50] = (_Float16)h;
        *hptr = (_Float16)h;
      }

      barrier_lds_only();
      cur ^= 1;
      preOff += pdelta;
      hptr += hstep;
    }
  }
#undef GSRC
}

// ---------------- K4: emission (R32: 256 blocks, pw staged ONCE per 128 tokens) ----------------
// Old: 4096 blocks x 26KB pws staging = 106 MB L2 traffic. New: 256 blocks,
// each handles 128 tokens via a 16-iteration loop -> staging 6.6 MB (16x cut).
// Dot math, order, and output layout byte-identical.
__global__ __launch_bounds__(256) void k_proj(const _Float16* __restrict__ hbuf,
                                              const float* __restrict__ pw,
                                              const float* __restrict__ pb,
                                              float* __restrict__ em) {
  __shared__ __align__(16) float pws[NTAGS * 204];   // 25.9 KB
  __shared__ float pbs[NTAGS];
  int tid = threadIdx.x;
  for (int i = tid; i < NTAGS * 2 * HDIM; i += 256) {
    int tag = i / (2 * HDIM);
    int k = i - tag * (2 * HDIM);
    pws[tag * 204 + k] = pw[i];
  }
  if (tid < NTAGS) pbs[tid] = pb[tid];
  __syncthreads();

  int tag = tid & 31;
  int tok8 = tid >> 5;                         // 0..7
  int tbase = blockIdx.x * 128;                // 256 blocks x 128 tokens
  const float4* w4 = (const float4*)&pws[tag * 204];
  float bias = pbs[tag];
  for (int it = 0; it < 16; it++) {
    int token = tbase + it * 8 + tok8;
    const uint4* h4 = (const uint4*)(hbuf + (size_t)token * 2 * HDIM);
    float acc = bias;
#pragma unroll
    for (int k = 0; k < 25; k++) {
      uint4 hv = h4[k];
      h2 a = __builtin_bit_cast(h2, hv.x);
      h2 bq = __builtin_bit_cast(h2, hv.y);
      h2 cq = __builtin_bit_cast(h2, hv.z);
      h2 d = __builtin_bit_cast(h2, hv.w);
      float4 w0 = w4[k * 2], w1 = w4[k * 2 + 1];
      acc += (float)a.x * w0.x + (float)a.y * w0.y + (float)bq.x * w0.z + (float)bq.y * w0.w
           + (float)cq.x * w1.x + (float)cq.y * w1.y + (float)d.x * w1.z + (float)d.y * w1.w;
    }
    em[(size_t)token * NTAGS + tag] = acc;
  }
}

// ---------------- K5: CRF forward + gold score + loss (R32: zero cross-lane on chain) ----------------
// R31 chain still carried 2x __shfl_xor(..,32) (ds_permute, ~120cyc latency
// each, serialized per step). Since both wave halves duplicate work anyway,
// each lane now reads ALL 32 la values from laS (8 broadcast ds_read_b128)
// and computes the full max/sum itself: trade +16 exps (~64cyc issue) for
// -240cyc of cross-lane latency. Chain = write + lgkm + 8 reads + VALU only.
// Max is exact (order-independent tree); sum is the same value set in a
// fixed different order (f32 reorder only — R30 validated reorder passes).
__global__ __launch_bounds__(64) void k_crf(const float* __restrict__ em,
                                            const float* __restrict__ trans,
                                            const int* __restrict__ mask,
                                            const int* __restrict__ y,
                                            float* __restrict__ out) {
  int b = blockIdx.x;
  int lane = threadIdx.x;
  int j = lane & 31;

  __shared__ __align__(16) float emS[SS * NTAGS];   // 32 KB
  __shared__ __align__(16) int mkS[SS];             // 1 KB
  __shared__ __align__(16) float laS[2][32];
  {
    const uint4* src = (const uint4*)(em + (size_t)b * SS * NTAGS);
#pragma unroll
    for (int p = 0; p < 32; p++) {
      uint4 t = src[p * 64 + lane];
      *(uint4*)&emS[(p * 64 + lane) * 4] = t;
    }
    uint4 mv = ((const uint4*)(mask + (size_t)b * SS))[lane];
    *(uint4*)&mkS[lane * 4] = mv;
  }
  barrier_lds_only();

  // ---- gold path score, 64 lanes (em from LDS) ----
  float sacc = 0.f;
  for (int s = lane; s < SS; s += 64) {
    int curt = y[b * SS + s];
    int prevt = (s == 0) ? TAG_START : y[b * SS + s - 1];
    float mk = (float)mkS[s];
    sacc += (emS[s * NTAGS + curt] + trans[prevt * NTAGS + curt]) * mk;
  }
#pragma unroll
  for (int off = 32; off > 0; off >>= 1) sacc += __shfl_down(sacc, off);
  float scoreYv = __shfl(sacc, 0) + trans[y[b * SS + SS - 1] * NTAGS + TAG_END];

  // full transition column: tcol[i] = T[i][j], 32 VGPRs
  float tcol[32];
#pragma unroll
  for (int i = 0; i < 32; i++) tcol[i] = trans[i * NTAGS + j];

  float la = (j == TAG_START) ? 0.f : NEGV;

  for (int s = 0; s < SS; s++) {
    float e0 = emS[s * NTAGS + j];
    float mkv = (float)mkS[s];

    if (lane < 32) laS[s & 1][lane] = la;
    asm volatile("s_waitcnt lgkmcnt(0)" ::: "memory");
    const float4* lp = (const float4*)&laS[s & 1][0];
    float4 t0 = lp[0], t1 = lp[1], t2 = lp[2], t3 = lp[3];
    float4 t4 = lp[4], t5 = lp[5], t6 = lp[6], t7 = lp[7];

    float v[32];
    v[0] = t0.x + tcol[0];   v[1] = t0.y + tcol[1];
    v[2] = t0.z + tcol[2];   v[3] = t0.w + tcol[3];
    v[4] = t1.x + tcol[4];   v[5] = t1.y + tcol[5];
    v[6] = t1.z + tcol[6];   v[7] = t1.w + tcol[7];
    v[8] = t2.x + tcol[8];   v[9] = t2.y + tcol[9];
    v[10] = t2.z + tcol[10]; v[11] = t2.w + tcol[11];
    v[12] = t3.x + tcol[12]; v[13] = t3.y + tcol[13];
    v[14] = t3.z + tcol[14]; v[15] = t3.w + tcol[15];
    v[16] = t4.x + tcol[16]; v[17] = t4.y + tcol[17];
    v[18] = t4.z + tcol[18]; v[19] = t4.w + tcol[19];
    v[20] = t5.x + tcol[20]; v[21] = t5.y + tcol[21];
    v[22] = t5.z + tcol[22]; v[23] = t5.w + tcol[23];
    v[24] = t6.x + tcol[24]; v[25] = t6.y + tcol[25];
    v[26] = t6.z + tcol[26]; v[27] = t6.w + tcol[27];
    v[28] = t7.x + tcol[28]; v[29] = t7.y + tcol[29];
    v[30] = t7.z + tcol[30]; v[31] = t7.w + tcol[31];

    // exact max, pairwise tree over all 32
    float mx[16];
#pragma unroll
    for (int k = 0; k < 16; k++) mx[k] = fmaxf(v[2 * k], v[2 * k + 1]);
#pragma unroll
    for (int st = 8; st > 0; st >>= 1)
#pragma unroll
      for (int k = 0; k < 8; k++)
        if (k < st) mx[k] = fmaxf(mx[k], mx[k + st]);
    float m = mx[0];

    // sum of exps, 4 accumulators (fixed order)
    float s0 = 0.f, s1 = 0.f, s2v = 0.f, s3 = 0.f;
#pragma unroll
    for (int k = 0; k < 32; k += 4) {
      s0 += __expf(v[k] - m);
      s1 += __expf(v[k + 1] - m);
      s2v += __expf(v[k + 2] - m);
      s3 += __expf(v[k + 3] - m);
    }
    float sum = (s0 + s1) + (s2v + s3);

    float la2 = m + __logf(sum) + e0;
    la = la2 * mkv + la * (1.f - mkv);
  }
  la += trans[j * NTAGS + TAG_END];

  // ---- final logsumexp over j (lanes 32-63 duplicate lanes 0-31) ----
  float mm = la;
#pragma unroll
  for (int off = 16; off > 0; off >>= 1) mm = fmaxf(mm, __shfl_xor(mm, off));
  float ss = __expf(la - mm);
#pragma unroll
  for (int off = 16; off > 0; off >>= 1) ss += __shfl_xor(ss, off);
  float total = mm + __logf(ss);
  if (lane == 0) atomicAdd(out, (total - scoreYv) * (1.0f / BB));
}

extern "C" void kernel_launch(void* const* d_in, const int* in_sizes, int n_in,
                              void* d_out, int out_size, void* d_ws, size_t ws_size,
                              hipStream_t stream) {
  const float* word_emb = (const float*)d_in[0];
  const float* char_emb = (const float*)d_in[1];
  const float* conv_w   = (const float*)d_in[2];
  const float* conv_b   = (const float*)d_in[3];
  const float* wih_f    = (const float*)d_in[4];
  const float* whh_f    = (const float*)d_in[5];
  const float* bih_f    = (const float*)d_in[6];
  const float* bhh_f    = (const float*)d_in[7];
  const float* wih_b    = (const float*)d_in[8];
  const float* whh_b    = (const float*)d_in[9];
  const float* bih_b    = (const float*)d_in[10];
  const float* bhh_b    = (const float*)d_in[11];
  const float* proj_w   = (const float*)d_in[12];
  const float* proj_b   = (const float*)d_in[13];
  const float* trans    = (const float*)d_in[14];
  const int* word_x     = (const int*)d_in[15];
  const int* char_x     = (const int*)d_in[16];
  const int* y          = (const int*)d_in[17];
  const int* mask       = (const int*)d_in[18];
  float* out = (float*)d_out;

  _Float16* x16   = (_Float16*)d_ws;                     // 32768*160 halves
  _Float16* w16   = x16 + (size_t)BB * SS * KPAD;        // 832*160 halves
  _Float16* preF  = w16 + (size_t)NROWS * KPAD;          // 32768*400 halves
  _Float16* preB  = preF + (size_t)BB * SS * GDIM;       // 32768*400 halves
  _Float16* hbuf  = preB + (size_t)BB * SS * GDIM;       // 32768*200 halves
  float* em       = (float*)(hbuf + (size_t)BB * SS * 2 * HDIM);  // 32768*32 f32

  k_pre<<<NB_PRE, 256, 0, stream>>>(word_emb, word_x, char_emb, conv_w, conv_b,
                                    char_x, wih_f, wih_b, x16, w16, out);
  k_pregemm<<<BB * SS / 64, 256, 0, stream>>>(x16, w16, bih_f, bhh_f,
                                              bih_b, bhh_b, preF, preB);
  k_lstm<<<256, 256, 0, stream>>>(preF, preB, whh_f, whh_b, hbuf);
  k_proj<<<256, 256, 0, stream>>>(hbuf, proj_w, proj_b, em);
  k_crf<<<BB, 64, 0, stream>>>(em, trans, mask, y, out);
}

// Round 16
// 495.419 us; speedup vs baseline: 1.0856x; 1.0856x over previous
//
#include <hip/hip_runtime.h>
#include <hip/hip_fp16.h>
#include <cstdint>
#include <cstddef>

#define BB 128
#define SS 256
#define LL 10
#define NTAGS 32
#define TAG_START 30
#define TAG_END 31
#define WDIM 100
#define CDIM 30
#define NFILT 30
#define HDIM 100
#define KIN 130      // LSTM_IN = WDIM + FILT
#define KPAD 160     // padded K for f16 GEMM operands
#define GDIM 400     // 4*H
#define NROWS 832    // 13*64 padded W rows
#define NEGV -10000.0f
#define CTOK 8       // tokens per charconv block

// fused-pre block ranges (R25: word branch vectorized)
#define NB_CONV (BB * SS / CTOK)               // 4096
#define NB_WORDA (BB * SS * 12 / 256)          // 1536: uint4 groups d in [0,96)
#define NB_WORDB (BB * SS * 20 / 256)          // 2560: tail d 96..99 + zeros [130,160)
#define NB_WCVT (NROWS * KPAD / 256)           // 520
#define NB_PRE  (NB_CONV + NB_WORDA + NB_WORDB + NB_WCVT)  // 8712

typedef _Float16 h2 __attribute__((ext_vector_type(2)));
typedef _Float16 f16x8 __attribute__((ext_vector_type(8)));
typedef float f32x4 __attribute__((ext_vector_type(4)));

#if __has_builtin(__builtin_amdgcn_fdot2)
#define HAVE_FDOT2 1
#else
#define HAVE_FDOT2 0
#endif

__device__ __forceinline__ float sigm(float x) { return 1.0f / (1.0f + __expf(-x)); }
__device__ __forceinline__ float tanh_fast(float x) { return 2.0f / (1.0f + __expf(-2.0f * x)) - 1.0f; }

// lgkm-only barrier (R15-proven): leaves global prefetch/store in flight.
__device__ __forceinline__ void barrier_lds_only() {
  asm volatile("s_waitcnt lgkmcnt(0)" ::: "memory");
  __builtin_amdgcn_s_barrier();
  asm volatile("" ::: "memory");
}

// ---------------- K1 fused: charconv | word gather | wcvt, by block range ----------------
__global__ __launch_bounds__(256) void k_pre(
    const float* __restrict__ wemb, const int* __restrict__ wx,
    const float* __restrict__ cemb, const float* __restrict__ convw,
    const float* __restrict__ convb, const int* __restrict__ cx,
    const float* __restrict__ wihF, const float* __restrict__ wihB,
    _Float16* __restrict__ x16, _Float16* __restrict__ w16,
    float* __restrict__ out) {
  int blk = blockIdx.x;
  int tid = threadIdx.x;
  if (blk == 0 && tid == 0) out[0] = 0.f;

  if (blk < NB_CONV) {
    int tok8 = tid >> 5;
    int f = tid & 31;
    int token0 = blk * CTOK;
    __shared__ float e[CTOK][LL * CDIM];
    __shared__ float cw[NFILT * 3 * CDIM];   // 2700 floats = 10.8 KB
    __shared__ float cb[NFILT];
    __shared__ int ci[CTOK][LL];
    if (tid < CTOK * LL) {
      int t = tid / LL, l = tid - t * LL;
      ci[t][l] = cx[(token0 + t) * LL + l];
    }
    for (int i = tid; i < NFILT * 3 * CDIM; i += 256) cw[i] = convw[i];
    if (tid < NFILT) cb[tid] = convb[tid];
    __syncthreads();
    for (int i = tid; i < CTOK * LL * CDIM; i += 256) {
      int t = i / (LL * CDIM);
      int r = i - t * (LL * CDIM);
      int l = r / CDIM, c = r - l * CDIM;
      e[t][l * CDIM + c] = cemb[ci[t][l] * CDIM + c];
    }
    __syncthreads();
    if (f < NFILT) {
      float d0[LL], d1[LL], d2[LL];
#pragma unroll
      for (int l = 0; l < LL; l++) { d0[l] = 0.f; d1[l] = 0.f; d2[l] = 0.f; }
      const float* et = &e[tok8][0];
      for (int c = 0; c < CDIM; c++) {
        float w0 = cw[(f * 3 + 0) * CDIM + c];
        float w1 = cw[(f * 3 + 1) * CDIM + c];
        float w2 = cw[(f * 3 + 2) * CDIM + c];
#pragma unroll
        for (int l = 0; l < LL; l++) {
          float ev = et[l * CDIM + c];
          d0[l] += ev * w0; d1[l] += ev * w1; d2[l] += ev * w2;
        }
      }
      float bias = cb[f];
      float m = -3.0e38f;
#pragma unroll
      for (int h = 0; h < LL + 2; h++) {
        float acc = bias;
        int j0 = h - 2, j1 = h - 1, j2 = h;
        if (j0 >= 0 && j0 < LL) acc += d0[j0];
        if (j1 >= 0 && j1 < LL) acc += d1[j1];
        if (j2 >= 0 && j2 < LL) acc += d2[j2];
        m = fmaxf(m, acc);
      }
      x16[(size_t)(token0 + tok8) * KPAD + WDIM + f] = (_Float16)m;
    }
  } else if (blk < NB_CONV + NB_WORDA) {
    // vectorized word gather: one uint4 (8 halves) per thread, d in [0,96)
    int idx = (blk - NB_CONV) * 256 + tid;
    int token = idx / 12;
    int g = idx - token * 12;
    const float* src = wemb + (size_t)wx[token] * WDIM + g * 8;
    float4 f0 = *(const float4*)(src);
    float4 f1 = *(const float4*)(src + 4);
    f16x8 v;
    v[0] = (_Float16)f0.x; v[1] = (_Float16)f0.y;
    v[2] = (_Float16)f0.z; v[3] = (_Float16)f0.w;
    v[4] = (_Float16)f1.x; v[5] = (_Float16)f1.y;
    v[6] = (_Float16)f1.z; v[7] = (_Float16)f1.w;
    *(f16x8*)&x16[(size_t)token * KPAD + g * 8] = v;
  } else if (blk < NB_CONV + NB_WORDA + NB_WORDB) {
    // tail: d 96..99 scalar wemb; zeros for d in [130,160) as uint pairs
    int idx = (blk - NB_CONV - NB_WORDA) * 256 + tid;
    int token = idx / 20;
    int u = idx - token * 20;
    if (u < 4) {
      x16[(size_t)token * KPAD + 96 + u] = (_Float16)wemb[(size_t)wx[token] * WDIM + 96 + u];
    } else if (u < 19) {
      *(uint32_t*)&x16[(size_t)token * KPAD + KIN + 2 * (u - 4)] = 0;
    }
  } else {
    int idx = (blk - NB_CONV - NB_WORDA - NB_WORDB) * 256 + tid;
    int n = idx / KPAD;
    int k = idx - n * KPAD;
    float v = 0.f;
    if (k < KIN && n < 2 * GDIM) {
      v = (n < GDIM) ? wihF[(size_t)n * KIN + k] : wihB[(size_t)(n - GDIM) * KIN + k];
    }
    w16[idx] = (_Float16)v;
  }
}

// ---------------- K2: pre = x @ wih^T + (bih+bhh), MFMA f16 (R25: n-loop-in-block) ----------------
__global__ __launch_bounds__(256) void k_pregemm(
    const _Float16* __restrict__ x16, const _Float16* __restrict__ w16,
    const float* __restrict__ bihF, const float* __restrict__ bhhF,
    const float* __restrict__ bihB, const float* __restrict__ bhhB,
    _Float16* __restrict__ preF, _Float16* __restrict__ preB) {
  __shared__ __align__(16) _Float16 Asl[64 * 168];      // 21.5 KB
  __shared__ __align__(16) _Float16 Bsl[2][64 * 168];   // 43 KB
  int m0 = blockIdx.x * 64;
  int tid = threadIdx.x;
  int lane = tid & 63, w = tid >> 6;
  int quad = lane >> 4, l15 = lane & 15;
  int r = tid >> 2;            // staging row 0..63
  int kk = (tid & 3) * 8;      // k offset within chunk

  const _Float16* xs = x16 + (size_t)(m0 + r) * KPAD + kk;
  const _Float16* ws = w16 + (size_t)r * KPAD + kk;
#pragma unroll
  for (int kc = 0; kc < 5; kc++) {
    *(f16x8*)&Asl[r * 168 + kc * 32 + kk] = *(const f16x8*)(xs + kc * 32);
    *(f16x8*)&Bsl[0][r * 168 + kc * 32 + kk] = *(const f16x8*)(ws + kc * 32);
  }
  __syncthreads();

  for (int nt = 0; nt < 13; nt++) {
    int cur = nt & 1;
    // prefetch next B tile into registers (stays in flight across compute)
    f16x8 nb0, nb1, nb2, nb3, nb4;
    if (nt + 1 < 13) {
      const _Float16* wn = w16 + (size_t)((nt + 1) * 64 + r) * KPAD + kk;
      nb0 = *(const f16x8*)(wn);
      nb1 = *(const f16x8*)(wn + 32);
      nb2 = *(const f16x8*)(wn + 64);
      nb3 = *(const f16x8*)(wn + 96);
      nb4 = *(const f16x8*)(wn + 128);
    }

    f32x4 acc[4];
#pragma unroll
    for (int i = 0; i < 4; i++) acc[i] = (f32x4){0.f, 0.f, 0.f, 0.f};
#pragma unroll
    for (int kc = 0; kc < 5; kc++) {
      f16x8 bfrag = *(const f16x8*)&Bsl[cur][(w * 16 + l15) * 168 + kc * 32 + quad * 8];
#pragma unroll
      for (int mt = 0; mt < 4; mt++) {
        f16x8 afrag = *(const f16x8*)&Asl[(mt * 16 + l15) * 168 + kc * 32 + quad * 8];
        acc[mt] = __builtin_amdgcn_mfma_f32_16x16x32_f16(afrag, bfrag, acc[mt], 0, 0, 0);
      }
    }

    int ng = nt * 64 + w * 16 + l15;  // this lane's output column
    if (ng < 2 * GDIM) {
      int dir = ng >= GDIM;
      int jb = dir ? ng - GDIM : ng;
      _Float16* dst = dir ? preB : preF;
      float bias = (dir ? bihB : bihF)[jb] + (dir ? bhhB : bhhF)[jb];
#pragma unroll
      for (int mt = 0; mt < 4; mt++) {
#pragma unroll
        for (int i = 0; i < 4; i++) {
          int m = m0 + mt * 16 + quad * 4 + i;
          dst[(size_t)m * GDIM + jb] = (_Float16)(acc[mt][i] + bias);
        }
      }
    }

    if (nt + 1 < 13) {
      asm volatile("s_waitcnt vmcnt(0)" ::: "memory");
      int nxt = cur ^ 1;   // buffer last READ in iteration nt-1; all waves past
      *(f16x8*)&Bsl[nxt][r * 168 + 0 * 32 + kk] = nb0;
      *(f16x8*)&Bsl[nxt][r * 168 + 1 * 32 + kk] = nb1;
      *(f16x8*)&Bsl[nxt][r * 168 + 2 * 32 + kk] = nb2;
      *(f16x8*)&Bsl[nxt][r * 168 + 3 * 32 + kk] = nb3;
      *(f16x8*)&Bsl[nxt][r * 168 + 4 * 32 + kk] = nb4;
      __syncthreads();
    }
  }
}

// ---------------- K3: recurrent LSTM scan (R21 fdot2 structure, best measured 164us) ----------------
#define CH 32
#define NCH (SS / CH)
__global__ __launch_bounds__(256, 1) void k_lstm(
    const _Float16* __restrict__ preF, const _Float16* __restrict__ preB,
    const float* __restrict__ whhF, const float* __restrict__ whhB,
    _Float16* __restrict__ hbuf) {
  int blk = blockIdx.x;              // 256 blocks
  int dir = blk >> 7;                // 0 fwd, 1 bwd
  int b = blk & 127;
  const _Float16* pre = dir ? preB : preF;
  const float* whh = dir ? whhB : whhF;
  int tid = threadIdx.x;
  int j = tid >> 1;                  // cell 0..127 (valid < 100)
  int kh = tid & 1;                  // k-half: [0,50) or [50,100)
  bool act = (j < HDIM);
  int jc = act ? j : 0;

  // ---- weight preload: wp[g][q] = whh[g*100+j][kh*50 + 2q .. +1] as half2 ----
  __half2 wp[4][25];
#pragma unroll
  for (int g = 0; g < 4; g++) {
    const float* wr = whh + (size_t)(g * HDIM + jc) * HDIM + kh * 50;
#pragma unroll
    for (int q = 0; q < 25; q++) {
      wp[g][q] = __floats2half2_rn(wr[2 * q], wr[2 * q + 1]);
    }
  }

  // ---- LDS: pre chunk buffer (28.7 KB) + h double buffer (512 B) ----
  __shared__ __align__(16) _Float16 preS[14336];   // 1792 uint4
  __shared__ __align__(16) _Float16 hsh[2][2][64];
  if (tid < 128) ((int*)hsh)[tid] = 0;
  float c = 0.f;

#define GSRC(ck) ((const uint4*)(pre + ((size_t)b * SS + (dir ? (SS - CH - (ck) * CH) : ((ck) * CH))) * GDIM))

  uint4 r0, r1, r2, r3, r4, r5, r6;
  {
    const uint4* s0 = GSRC(0);
    r0 = s0[0 * 256 + tid]; r1 = s0[1 * 256 + tid]; r2 = s0[2 * 256 + tid];
    r3 = s0[3 * 256 + tid]; r4 = s0[4 * 256 + tid]; r5 = s0[5 * 256 + tid];
    r6 = s0[6 * 256 + tid];
  }

  _Float16* hptr = hbuf + ((size_t)b * SS + (dir ? (SS - 1) : 0)) * (2 * HDIM) + dir * HDIM + jc;
  const intptr_t hstep = dir ? -(intptr_t)(2 * HDIM) : (intptr_t)(2 * HDIM);

  int cur = 0;
  for (int ck = 0; ck < NCH; ck++) {
    asm volatile("s_waitcnt vmcnt(0)" ::: "memory");   // staged regs landed
    *(uint4*)&preS[(0 * 256 + tid) * 8] = r0;
    *(uint4*)&preS[(1 * 256 + tid) * 8] = r1;
    *(uint4*)&preS[(2 * 256 + tid) * 8] = r2;
    *(uint4*)&preS[(3 * 256 + tid) * 8] = r3;
    *(uint4*)&preS[(4 * 256 + tid) * 8] = r4;
    *(uint4*)&preS[(5 * 256 + tid) * 8] = r5;
    *(uint4*)&preS[(6 * 256 + tid) * 8] = r6;
    if (ck + 1 < NCH) {
      const uint4* snx = GSRC(ck + 1);
      r0 = snx[0 * 256 + tid]; r1 = snx[1 * 256 + tid]; r2 = snx[2 * 256 + tid];
      r3 = snx[3 * 256 + tid]; r4 = snx[4 * 256 + tid]; r5 = snx[5 * 256 + tid];
      r6 = snx[6 * 256 + tid];
    }
    barrier_lds_only();   // preS (and hsh zeros on ck=0) visible to all waves

    int preOff = (dir ? (CH - 1) * GDIM : 0) + kh * 200 + jc;
    const int pdelta = dir ? -GDIM : GDIM;

    for (int s2 = 0; s2 < CH; s2++) {
      float paF = (float)preS[preOff];
      float pbF = (float)preS[preOff + 100];

      // h of previous step: 50 halves of this lane's k-half (broadcast reads)
      const _Float16* hseg = &hsh[cur][kh][0];
      uint4 hv0 = *(const uint4*)(hseg);
      uint4 hv1 = *(const uint4*)(hseg + 8);
      uint4 hv2 = *(const uint4*)(hseg + 16);
      uint4 hv3 = *(const uint4*)(hseg + 24);
      uint4 hv4 = *(const uint4*)(hseg + 32);
      uint4 hv5 = *(const uint4*)(hseg + 40);
      uint32_t hv6 = *(const uint32_t*)(hseg + 48);
      __half2 hp[25];
      hp[0]  = __builtin_bit_cast(__half2, hv0.x);
      hp[1]  = __builtin_bit_cast(__half2, hv0.y);
      hp[2]  = __builtin_bit_cast(__half2, hv0.z);
      hp[3]  = __builtin_bit_cast(__half2, hv0.w);
      hp[4]  = __builtin_bit_cast(__half2, hv1.x);
      hp[5]  = __builtin_bit_cast(__half2, hv1.y);
      hp[6]  = __builtin_bit_cast(__half2, hv1.z);
      hp[7]  = __builtin_bit_cast(__half2, hv1.w);
      hp[8]  = __builtin_bit_cast(__half2, hv2.x);
      hp[9]  = __builtin_bit_cast(__half2, hv2.y);
      hp[10] = __builtin_bit_cast(__half2, hv2.z);
      hp[11] = __builtin_bit_cast(__half2, hv2.w);
      hp[12] = __builtin_bit_cast(__half2, hv3.x);
      hp[13] = __builtin_bit_cast(__half2, hv3.y);
      hp[14] = __builtin_bit_cast(__half2, hv3.z);
      hp[15] = __builtin_bit_cast(__half2, hv3.w);
      hp[16] = __builtin_bit_cast(__half2, hv4.x);
      hp[17] = __builtin_bit_cast(__half2, hv4.y);
      hp[18] = __builtin_bit_cast(__half2, hv4.z);
      hp[19] = __builtin_bit_cast(__half2, hv4.w);
      hp[20] = __builtin_bit_cast(__half2, hv5.x);
      hp[21] = __builtin_bit_cast(__half2, hv5.y);
      hp[22] = __builtin_bit_cast(__half2, hv5.z);
      hp[23] = __builtin_bit_cast(__half2, hv5.w);
      hp[24] = __builtin_bit_cast(__half2, hv6);

      // 4-gate partial dots over this lane's 50 k values
      float racc[4];
#if HAVE_FDOT2
#pragma unroll
      for (int g = 0; g < 4; g++) {
        float a0 = 0.f, a1 = 0.f;
#pragma unroll
        for (int q = 0; q < 25; q += 2)
          a0 = __builtin_amdgcn_fdot2(__builtin_bit_cast(h2, wp[g][q]),
                                      __builtin_bit_cast(h2, hp[q]), a0, false);
#pragma unroll
        for (int q = 1; q < 25; q += 2)
          a1 = __builtin_amdgcn_fdot2(__builtin_bit_cast(h2, wp[g][q]),
                                      __builtin_bit_cast(h2, hp[q]), a1, false);
        racc[g] = a0 + a1;
      }
#else
      __half2 z = __floats2half2_rn(0.f, 0.f);
#pragma unroll
      for (int g = 0; g < 4; g++) {
        __half2 a0 = z, a1 = z;
#pragma unroll
        for (int q = 0; q < 25; q += 2) a0 = __hfma2(wp[g][q], hp[q], a0);
#pragma unroll
        for (int q = 1; q < 25; q += 2) a1 = __hfma2(wp[g][q], hp[q], a1);
        racc[g] = (__low2float(a0) + __high2float(a0)) +
                  (__low2float(a1) + __high2float(a1));
      }
#endif

      // add pre (each lane of the pair contributes 2 gates), then pair-reduce
      if (kh == 0) { racc[0] += paF; racc[1] += pbF; }
      else         { racc[2] += paF; racc[3] += pbF; }
#pragma unroll
      for (int g = 0; g < 4; g++) racc[g] += __shfl_xor(racc[g], 1);

      // activations (both lanes of the pair compute identically; no divergence)
      float ig = sigm(racc[0]), fg = sigm(racc[1]);
      float g2 = tanh_fast(racc[2]), og = sigm(racc[3]);
      c = fg * c + ig * g2;
      float h = og * tanh_fast(c);

      if (act && kh == 0) {
        int seg = (j >= 50) ? 1 : 0;
        hsh[cur ^ 1][seg][j - seg * 50] = (_Float16)h;
        *hptr = (_Float16)h;
      }

      barrier_lds_only();
      cur ^= 1;
      preOff += pdelta;
      hptr += hstep;
    }
  }
#undef GSRC
}

// ---------------- K4: emission = [h_f,h_b] @ proj_w^T + proj_b (R25/R31 form — proven 470us run) ----------------
// R33: REVERT the R32 restructure. 4096->256 blocks was a 16x TLP cut with
// 16 serial dependent-load iterations at ~1 block/CU -- the R19/R28 occupancy
// failure mode; it cost ~+50-65us. This form is proven in the 470us run.
__global__ __launch_bounds__(256) void k_proj(const _Float16* __restrict__ hbuf,
                                              const float* __restrict__ pw,
                                              const float* __restrict__ pb,
                                              float* __restrict__ em) {
  __shared__ __align__(16) float pws[NTAGS * 204];   // 25.9 KB
  __shared__ float pbs[NTAGS];
  int tid = threadIdx.x;
  for (int i = tid; i < NTAGS * 2 * HDIM; i += 256) {
    int tag = i / (2 * HDIM);
    int k = i - tag * (2 * HDIM);
    pws[tag * 204 + k] = pw[i];
  }
  if (tid < NTAGS) pbs[tid] = pb[tid];
  __syncthreads();

  int idx = blockIdx.x * blockDim.x + tid;  // token*32 + tag
  if (idx >= BB * SS * NTAGS) return;
  int token = idx >> 5, tag = idx & 31;
  const uint4* h4 = (const uint4*)(hbuf + (size_t)token * 2 * HDIM);
  const float4* w4 = (const float4*)&pws[tag * 204];
  float acc = pbs[tag];
#pragma unroll
  for (int k = 0; k < 25; k++) {
    uint4 hv = h4[k];
    h2 a = __builtin_bit_cast(h2, hv.x);
    h2 bq = __builtin_bit_cast(h2, hv.y);
    h2 cq = __builtin_bit_cast(h2, hv.z);
    h2 d = __builtin_bit_cast(h2, hv.w);
    float4 w0 = w4[k * 2], w1 = w4[k * 2 + 1];
    acc += (float)a.x * w0.x + (float)a.y * w0.y + (float)bq.x * w0.z + (float)bq.y * w0.w
         + (float)cq.x * w1.x + (float)cq.y * w1.y + (float)d.x * w1.z + (float)d.y * w1.w;
  }
  em[idx] = acc;
}

// ---------------- K5: CRF (R32 zero-cross-lane chain — KEPT, now isolated A/B) ----------------
// The only unproven component this round. Chain: write + lgkm + 8 broadcast
// b128 reads + pure VALU (no shfl). If this is the predicted win, total lands
// ~455-465; if not, revert next round and lock the R31 set.
__global__ __launch_bounds__(64) void k_crf(const float* __restrict__ em,
                                            const float* __restrict__ trans,
                                            const int* __restrict__ mask,
                                            const int* __restrict__ y,
                                            float* __restrict__ out) {
  int b = blockIdx.x;
  int lane = threadIdx.x;
  int j = lane & 31;

  __shared__ __align__(16) float emS[SS * NTAGS];   // 32 KB
  __shared__ __align__(16) int mkS[SS];             // 1 KB
  __shared__ __align__(16) float laS[2][32];
  {
    const uint4* src = (const uint4*)(em + (size_t)b * SS * NTAGS);
#pragma unroll
    for (int p = 0; p < 32; p++) {
      uint4 t = src[p * 64 + lane];
      *(uint4*)&emS[(p * 64 + lane) * 4] = t;
    }
    uint4 mv = ((const uint4*)(mask + (size_t)b * SS))[lane];
    *(uint4*)&mkS[lane * 4] = mv;
  }
  barrier_lds_only();

  // ---- gold path score, 64 lanes (em from LDS) ----
  float sacc = 0.f;
  for (int s = lane; s < SS; s += 64) {
    int curt = y[b * SS + s];
    int prevt = (s == 0) ? TAG_START : y[b * SS + s - 1];
    float mk = (float)mkS[s];
    sacc += (emS[s * NTAGS + curt] + trans[prevt * NTAGS + curt]) * mk;
  }
#pragma unroll
  for (int off = 32; off > 0; off >>= 1) sacc += __shfl_down(sacc, off);
  float scoreYv = __shfl(sacc, 0) + trans[y[b * SS + SS - 1] * NTAGS + TAG_END];

  // full transition column: tcol[i] = T[i][j], 32 VGPRs
  float tcol[32];
#pragma unroll
  for (int i = 0; i < 32; i++) tcol[i] = trans[i * NTAGS + j];

  float la = (j == TAG_START) ? 0.f : NEGV;

  for (int s = 0; s < SS; s++) {
    float e0 = emS[s * NTAGS + j];
    float mkv = (float)mkS[s];

    if (lane < 32) laS[s & 1][lane] = la;
    asm volatile("s_waitcnt lgkmcnt(0)" ::: "memory");
    const float4* lp = (const float4*)&laS[s & 1][0];
    float4 t0 = lp[0], t1 = lp[1], t2 = lp[2], t3 = lp[3];
    float4 t4 = lp[4], t5 = lp[5], t6 = lp[6], t7 = lp[7];

    float v[32];
    v[0] = t0.x + tcol[0];   v[1] = t0.y + tcol[1];
    v[2] = t0.z + tcol[2];   v[3] = t0.w + tcol[3];
    v[4] = t1.x + tcol[4];   v[5] = t1.y + tcol[5];
    v[6] = t1.z + tcol[6];   v[7] = t1.w + tcol[7];
    v[8] = t2.x + tcol[8];   v[9] = t2.y + tcol[9];
    v[10] = t2.z + tcol[10]; v[11] = t2.w + tcol[11];
    v[12] = t3.x + tcol[12]; v[13] = t3.y + tcol[13];
    v[14] = t3.z + tcol[14]; v[15] = t3.w + tcol[15];
    v[16] = t4.x + tcol[16]; v[17] = t4.y + tcol[17];
    v[18] = t4.z + tcol[18]; v[19] = t4.w + tcol[19];
    v[20] = t5.x + tcol[20]; v[21] = t5.y + tcol[21];
    v[22] = t5.z + tcol[22]; v[23] = t5.w + tcol[23];
    v[24] = t6.x + tcol[24]; v[25] = t6.y + tcol[25];
    v[26] = t6.z + tcol[26]; v[27] = t6.w + tcol[27];
    v[28] = t7.x + tcol[28]; v[29] = t7.y + tcol[29];
    v[30] = t7.z + tcol[30]; v[31] = t7.w + tcol[31];

    // exact max, pairwise tree over all 32
    float mx[16];
#pragma unroll
    for (int k = 0; k < 16; k++) mx[k] = fmaxf(v[2 * k], v[2 * k + 1]);
#pragma unroll
    for (int st = 8; st > 0; st >>= 1)
#pragma unroll
      for (int k = 0; k < 8; k++)
        if (k < st) mx[k] = fmaxf(mx[k], mx[k + st]);
    float m = mx[0];

    // sum of exps, 4 accumulators (fixed order)
    float s0 = 0.f, s1 = 0.f, s2v = 0.f, s3 = 0.f;
#pragma unroll
    for (int k = 0; k < 32; k += 4) {
      s0 += __expf(v[k] - m);
      s1 += __expf(v[k + 1] - m);
      s2v += __expf(v[k + 2] - m);
      s3 += __expf(v[k + 3] - m);
    }
    float sum = (s0 + s1) + (s2v + s3);

    float la2 = m + __logf(sum) + e0;
    la = la2 * mkv + la * (1.f - mkv);
  }
  la += trans[j * NTAGS + TAG_END];

  // ---- final logsumexp over j (lanes 32-63 duplicate lanes 0-31) ----
  float mm = la;
#pragma unroll
  for (int off = 16; off > 0; off >>= 1) mm = fmaxf(mm, __shfl_xor(mm, off));
  float ss = __expf(la - mm);
#pragma unroll
  for (int off = 16; off > 0; off >>= 1) ss += __shfl_xor(ss, off);
  float total = mm + __logf(ss);
  if (lane == 0) atomicAdd(out, (total - scoreYv) * (1.0f / BB));
}

extern "C" void kernel_launch(void* const* d_in, const int* in_sizes, int n_in,
                              void* d_out, int out_size, void* d_ws, size_t ws_size,
                              hipStream_t stream) {
  const float* word_emb = (const float*)d_in[0];
  const float* char_emb = (const float*)d_in[1];
  const float* conv_w   = (const float*)d_in[2];
  const float* conv_b   = (const float*)d_in[3];
  const float* wih_f    = (const float*)d_in[4];
  const float* whh_f    = (const float*)d_in[5];
  const float* bih_f    = (const float*)d_in[6];
  const float* bhh_f    = (const float*)d_in[7];
  const float* wih_b    = (const float*)d_in[8];
  const float* whh_b    = (const float*)d_in[9];
  const float* bih_b    = (const float*)d_in[10];
  const float* bhh_b    = (const float*)d_in[11];
  const float* proj_w   = (const float*)d_in[12];
  const float* proj_b   = (const float*)d_in[13];
  const float* trans    = (const float*)d_in[14];
  const int* word_x     = (const int*)d_in[15];
  const int* char_x     = (const int*)d_in[16];
  const int* y          = (const int*)d_in[17];
  const int* mask       = (const int*)d_in[18];
  float* out = (float*)d_out;

  _Float16* x16   = (_Float16*)d_ws;                     // 32768*160 halves
  _Float16* w16   = x16 + (size_t)BB * SS * KPAD;        // 832*160 halves
  _Float16* preF  = w16 + (size_t)NROWS * KPAD;          // 32768*400 halves
  _Float16* preB  = preF + (size_t)BB * SS * GDIM;       // 32768*400 halves
  _Float16* hbuf  = preB + (size_t)BB * SS * GDIM;       // 32768*200 halves
  float* em       = (float*)(hbuf + (size_t)BB * SS * 2 * HDIM);  // 32768*32 f32

  k_pre<<<NB_PRE, 256, 0, stream>>>(word_emb, word_x, char_emb, conv_w, conv_b,
                                    char_x, wih_f, wih_b, x16, w16, out);
  k_pregemm<<<BB * SS / 64, 256, 0, stream>>>(x16, w16, bih_f, bhh_f,
                                              bih_b, bhh_b, preF, preB);
  k_lstm<<<256, 256, 0, stream>>>(preF, preB, whh_f, whh_b, hbuf);
  k_proj<<<(BB * SS * NTAGS + 255) / 256, 256, 0, stream>>>(hbuf, proj_w, proj_b, em);
  k_crf<<<BB, 64, 0, stream>>>(em, trans, mask, y, out);
}

// Round 17
// 467.689 us; speedup vs baseline: 1.1499x; 1.0593x over previous
//
#include <hip/hip_runtime.h>
#include <hip/hip_fp16.h>
#include <cstdint>
#include <cstddef>

#define BB 128
#define SS 256
#define LL 10
#define NTAGS 32
#define TAG_START 30
#define TAG_END 31
#define WDIM 100
#define CDIM 30
#define NFILT 30
#define HDIM 100
#define KIN 130      // LSTM_IN = WDIM + FILT
#define KPAD 160     // padded K for f16 GEMM operands
#define GDIM 400     // 4*H
#define NROWS 832    // 13*64 padded W rows
#define NEGV -10000.0f
#define CTOK 16      // tokens per charconv block (R34: 8 -> 16, 512 threads)

// fused-pre block ranges (R34: 512-thread blocks)
#define NB_CONV (BB * SS / CTOK)               // 2048
#define NB_WORDA (BB * SS * 12 / 512)          // 768: uint4 groups d in [0,96)
#define NB_WORDB (BB * SS * 20 / 512)          // 1280: tail d 96..99 + zeros [130,160)
#define NB_WCVT (NROWS * KPAD / 512)           // 260
#define NB_PRE  (NB_CONV + NB_WORDA + NB_WORDB + NB_WCVT)  // 4356

typedef _Float16 h2 __attribute__((ext_vector_type(2)));
typedef _Float16 f16x8 __attribute__((ext_vector_type(8)));
typedef float f32x4 __attribute__((ext_vector_type(4)));

#if __has_builtin(__builtin_amdgcn_fdot2)
#define HAVE_FDOT2 1
#else
#define HAVE_FDOT2 0
#endif

__device__ __forceinline__ float sigm(float x) { return 1.0f / (1.0f + __expf(-x)); }
__device__ __forceinline__ float tanh_fast(float x) { return 2.0f / (1.0f + __expf(-2.0f * x)) - 1.0f; }

// lgkm-only barrier (R15-proven): leaves global prefetch/store in flight.
__device__ __forceinline__ void barrier_lds_only() {
  asm volatile("s_waitcnt lgkmcnt(0)" ::: "memory");
  __builtin_amdgcn_s_barrier();
  asm volatile("" ::: "memory");
}

// ---------------- K1 fused: charconv | word gather | wcvt, by block range ----------------
// R34 delta: conv branch at CTOK=16 / 512 threads -- convw is staged 2048x
// instead of 4096x (44 -> 22 MB L2 staging), launch count 8712 -> 4356.
// Hot-loop math per thread unchanged.
__global__ __launch_bounds__(512) void k_pre(
    const float* __restrict__ wemb, const int* __restrict__ wx,
    const float* __restrict__ cemb, const float* __restrict__ convw,
    const float* __restrict__ convb, const int* __restrict__ cx,
    const float* __restrict__ wihF, const float* __restrict__ wihB,
    _Float16* __restrict__ x16, _Float16* __restrict__ w16,
    float* __restrict__ out) {
  int blk = blockIdx.x;
  int tid = threadIdx.x;
  if (blk == 0 && tid == 0) out[0] = 0.f;

  if (blk < NB_CONV) {
    int tok = tid >> 5;                  // 0..15
    int f = tid & 31;
    int token0 = blk * CTOK;
    __shared__ float e[CTOK][LL * CDIM];              // 19.2 KB
    __shared__ float cw[NFILT * 3 * CDIM];            // 10.8 KB
    __shared__ float cb[NFILT];
    __shared__ int ci[CTOK][LL];
    if (tid < CTOK * LL) {
      int t = tid / LL, l = tid - t * LL;
      ci[t][l] = cx[(token0 + t) * LL + l];
    }
    for (int i = tid; i < NFILT * 3 * CDIM; i += 512) cw[i] = convw[i];
    if (tid < NFILT) cb[tid] = convb[tid];
    __syncthreads();
    for (int i = tid; i < CTOK * LL * CDIM; i += 512) {
      int t = i / (LL * CDIM);
      int r = i - t * (LL * CDIM);
      int l = r / CDIM, c = r - l * CDIM;
      e[t][l * CDIM + c] = cemb[ci[t][l] * CDIM + c];
    }
    __syncthreads();
    if (f < NFILT) {
      float d0[LL], d1[LL], d2[LL];
#pragma unroll
      for (int l = 0; l < LL; l++) { d0[l] = 0.f; d1[l] = 0.f; d2[l] = 0.f; }
      const float* et = &e[tok][0];
      for (int c = 0; c < CDIM; c++) {
        float w0 = cw[(f * 3 + 0) * CDIM + c];
        float w1 = cw[(f * 3 + 1) * CDIM + c];
        float w2 = cw[(f * 3 + 2) * CDIM + c];
#pragma unroll
        for (int l = 0; l < LL; l++) {
          float ev = et[l * CDIM + c];
          d0[l] += ev * w0; d1[l] += ev * w1; d2[l] += ev * w2;
        }
      }
      float bias = cb[f];
      float m = -3.0e38f;
#pragma unroll
      for (int h = 0; h < LL + 2; h++) {
        float acc = bias;
        int j0 = h - 2, j1 = h - 1, j2 = h;
        if (j0 >= 0 && j0 < LL) acc += d0[j0];
        if (j1 >= 0 && j1 < LL) acc += d1[j1];
        if (j2 >= 0 && j2 < LL) acc += d2[j2];
        m = fmaxf(m, acc);
      }
      x16[(size_t)(token0 + tok) * KPAD + WDIM + f] = (_Float16)m;
    }
  } else if (blk < NB_CONV + NB_WORDA) {
    // vectorized word gather: one uint4 (8 halves) per thread, d in [0,96)
    int idx = (blk - NB_CONV) * 512 + tid;
    int token = idx / 12;
    int g = idx - token * 12;
    const float* src = wemb + (size_t)wx[token] * WDIM + g * 8;
    float4 f0 = *(const float4*)(src);
    float4 f1 = *(const float4*)(src + 4);
    f16x8 v;
    v[0] = (_Float16)f0.x; v[1] = (_Float16)f0.y;
    v[2] = (_Float16)f0.z; v[3] = (_Float16)f0.w;
    v[4] = (_Float16)f1.x; v[5] = (_Float16)f1.y;
    v[6] = (_Float16)f1.z; v[7] = (_Float16)f1.w;
    *(f16x8*)&x16[(size_t)token * KPAD + g * 8] = v;
  } else if (blk < NB_CONV + NB_WORDA + NB_WORDB) {
    // tail: d 96..99 scalar wemb; zeros for d in [130,160) as uint pairs
    int idx = (blk - NB_CONV - NB_WORDA) * 512 + tid;
    int token = idx / 20;
    int u = idx - token * 20;
    if (u < 4) {
      x16[(size_t)token * KPAD + 96 + u] = (_Float16)wemb[(size_t)wx[token] * WDIM + 96 + u];
    } else if (u < 19) {
      *(uint32_t*)&x16[(size_t)token * KPAD + KIN + 2 * (u - 4)] = 0;
    }
  } else {
    int idx = (blk - NB_CONV - NB_WORDA - NB_WORDB) * 512 + tid;
    int n = idx / KPAD;
    int k = idx - n * KPAD;
    float v = 0.f;
    if (k < KIN && n < 2 * GDIM) {
      v = (n < GDIM) ? wihF[(size_t)n * KIN + k] : wihB[(size_t)(n - GDIM) * KIN + k];
    }
    w16[idx] = (_Float16)v;
  }
}

// ---------------- K2: pre = x @ wih^T + (bih+bhh), MFMA f16 (R25: n-loop-in-block) ----------------
__global__ __launch_bounds__(256) void k_pregemm(
    const _Float16* __restrict__ x16, const _Float16* __restrict__ w16,
    const float* __restrict__ bihF, const float* __restrict__ bhhF,
    const float* __restrict__ bihB, const float* __restrict__ bhhB,
    _Float16* __restrict__ preF, _Float16* __restrict__ preB) {
  __shared__ __align__(16) _Float16 Asl[64 * 168];      // 21.5 KB
  __shared__ __align__(16) _Float16 Bsl[2][64 * 168];   // 43 KB
  int m0 = blockIdx.x * 64;
  int tid = threadIdx.x;
  int lane = tid & 63, w = tid >> 6;
  int quad = lane >> 4, l15 = lane & 15;
  int r = tid >> 2;            // staging row 0..63
  int kk = (tid & 3) * 8;      // k offset within chunk

  const _Float16* xs = x16 + (size_t)(m0 + r) * KPAD + kk;
  const _Float16* ws = w16 + (size_t)r * KPAD + kk;
#pragma unroll
  for (int kc = 0; kc < 5; kc++) {
    *(f16x8*)&Asl[r * 168 + kc * 32 + kk] = *(const f16x8*)(xs + kc * 32);
    *(f16x8*)&Bsl[0][r * 168 + kc * 32 + kk] = *(const f16x8*)(ws + kc * 32);
  }
  __syncthreads();

  for (int nt = 0; nt < 13; nt++) {
    int cur = nt & 1;
    // prefetch next B tile into registers (stays in flight across compute)
    f16x8 nb0, nb1, nb2, nb3, nb4;
    if (nt + 1 < 13) {
      const _Float16* wn = w16 + (size_t)((nt + 1) * 64 + r) * KPAD + kk;
      nb0 = *(const f16x8*)(wn);
      nb1 = *(const f16x8*)(wn + 32);
      nb2 = *(const f16x8*)(wn + 64);
      nb3 = *(const f16x8*)(wn + 96);
      nb4 = *(const f16x8*)(wn + 128);
    }

    f32x4 acc[4];
#pragma unroll
    for (int i = 0; i < 4; i++) acc[i] = (f32x4){0.f, 0.f, 0.f, 0.f};
#pragma unroll
    for (int kc = 0; kc < 5; kc++) {
      f16x8 bfrag = *(const f16x8*)&Bsl[cur][(w * 16 + l15) * 168 + kc * 32 + quad * 8];
#pragma unroll
      for (int mt = 0; mt < 4; mt++) {
        f16x8 afrag = *(const f16x8*)&Asl[(mt * 16 + l15) * 168 + kc * 32 + quad * 8];
        acc[mt] = __builtin_amdgcn_mfma_f32_16x16x32_f16(afrag, bfrag, acc[mt], 0, 0, 0);
      }
    }

    int ng = nt * 64 + w * 16 + l15;  // this lane's output column
    if (ng < 2 * GDIM) {
      int dir = ng >= GDIM;
      int jb = dir ? ng - GDIM : ng;
      _Float16* dst = dir ? preB : preF;
      float bias = (dir ? bihB : bihF)[jb] + (dir ? bhhB : bhhF)[jb];
#pragma unroll
      for (int mt = 0; mt < 4; mt++) {
#pragma unroll
        for (int i = 0; i < 4; i++) {
          int m = m0 + mt * 16 + quad * 4 + i;
          dst[(size_t)m * GDIM + jb] = (_Float16)(acc[mt][i] + bias);
        }
      }
    }

    if (nt + 1 < 13) {
      asm volatile("s_waitcnt vmcnt(0)" ::: "memory");
      int nxt = cur ^ 1;   // buffer last READ in iteration nt-1; all waves past
      *(f16x8*)&Bsl[nxt][r * 168 + 0 * 32 + kk] = nb0;
      *(f16x8*)&Bsl[nxt][r * 168 + 1 * 32 + kk] = nb1;
      *(f16x8*)&Bsl[nxt][r * 168 + 2 * 32 + kk] = nb2;
      *(f16x8*)&Bsl[nxt][r * 168 + 3 * 32 + kk] = nb3;
      *(f16x8*)&Bsl[nxt][r * 168 + 4 * 32 + kk] = nb4;
      __syncthreads();
    }
  }
}

// ---------------- K3: recurrent LSTM scan (R21 fdot2 structure, best measured 164us) ----------------
#define CH 32
#define NCH (SS / CH)
__global__ __launch_bounds__(256, 1) void k_lstm(
    const _Float16* __restrict__ preF, const _Float16* __restrict__ preB,
    const float* __restrict__ whhF, const float* __restrict__ whhB,
    _Float16* __restrict__ hbuf) {
  int blk = blockIdx.x;              // 256 blocks
  int dir = blk >> 7;                // 0 fwd, 1 bwd
  int b = blk & 127;
  const _Float16* pre = dir ? preB : preF;
  const float* whh = dir ? whhB : whhF;
  int tid = threadIdx.x;
  int j = tid >> 1;                  // cell 0..127 (valid < 100)
  int kh = tid & 1;                  // k-half: [0,50) or [50,100)
  bool act = (j < HDIM);
  int jc = act ? j : 0;

  // ---- weight preload: wp[g][q] = whh[g*100+j][kh*50 + 2q .. +1] as half2 ----
  __half2 wp[4][25];
#pragma unroll
  for (int g = 0; g < 4; g++) {
    const float* wr = whh + (size_t)(g * HDIM + jc) * HDIM + kh * 50;
#pragma unroll
    for (int q = 0; q < 25; q++) {
      wp[g][q] = __floats2half2_rn(wr[2 * q], wr[2 * q + 1]);
    }
  }

  // ---- LDS: pre chunk buffer (28.7 KB) + h double buffer (512 B) ----
  __shared__ __align__(16) _Float16 preS[14336];   // 1792 uint4
  __shared__ __align__(16) _Float16 hsh[2][2][64];
  if (tid < 128) ((int*)hsh)[tid] = 0;
  float c = 0.f;

#define GSRC(ck) ((const uint4*)(pre + ((size_t)b * SS + (dir ? (SS - CH - (ck) * CH) : ((ck) * CH))) * GDIM))

  uint4 r0, r1, r2, r3, r4, r5, r6;
  {
    const uint4* s0 = GSRC(0);
    r0 = s0[0 * 256 + tid]; r1 = s0[1 * 256 + tid]; r2 = s0[2 * 256 + tid];
    r3 = s0[3 * 256 + tid]; r4 = s0[4 * 256 + tid]; r5 = s0[5 * 256 + tid];
    r6 = s0[6 * 256 + tid];
  }

  _Float16* hptr = hbuf + ((size_t)b * SS + (dir ? (SS - 1) : 0)) * (2 * HDIM) + dir * HDIM + jc;
  const intptr_t hstep = dir ? -(intptr_t)(2 * HDIM) : (intptr_t)(2 * HDIM);

  int cur = 0;
  for (int ck = 0; ck < NCH; ck++) {
    asm volatile("s_waitcnt vmcnt(0)" ::: "memory");   // staged regs landed
    *(uint4*)&preS[(0 * 256 + tid) * 8] = r0;
    *(uint4*)&preS[(1 * 256 + tid) * 8] = r1;
    *(uint4*)&preS[(2 * 256 + tid) * 8] = r2;
    *(uint4*)&preS[(3 * 256 + tid) * 8] = r3;
    *(uint4*)&preS[(4 * 256 + tid) * 8] = r4;
    *(uint4*)&preS[(5 * 256 + tid) * 8] = r5;
    *(uint4*)&preS[(6 * 256 + tid) * 8] = r6;
    if (ck + 1 < NCH) {
      const uint4* snx = GSRC(ck + 1);
      r0 = snx[0 * 256 + tid]; r1 = snx[1 * 256 + tid]; r2 = snx[2 * 256 + tid];
      r3 = snx[3 * 256 + tid]; r4 = snx[4 * 256 + tid]; r5 = snx[5 * 256 + tid];
      r6 = snx[6 * 256 + tid];
    }
    barrier_lds_only();   // preS (and hsh zeros on ck=0) visible to all waves

    int preOff = (dir ? (CH - 1) * GDIM : 0) + kh * 200 + jc;
    const int pdelta = dir ? -GDIM : GDIM;

    for (int s2 = 0; s2 < CH; s2++) {
      float paF = (float)preS[preOff];
      float pbF = (float)preS[preOff + 100];

      // h of previous step: 50 halves of this lane's k-half (broadcast reads)
      const _Float16* hseg = &hsh[cur][kh][0];
      uint4 hv0 = *(const uint4*)(hseg);
      uint4 hv1 = *(const uint4*)(hseg + 8);
      uint4 hv2 = *(const uint4*)(hseg + 16);
      uint4 hv3 = *(const uint4*)(hseg + 24);
      uint4 hv4 = *(const uint4*)(hseg + 32);
      uint4 hv5 = *(const uint4*)(hseg + 40);
      uint32_t hv6 = *(const uint32_t*)(hseg + 48);
      __half2 hp[25];
      hp[0]  = __builtin_bit_cast(__half2, hv0.x);
      hp[1]  = __builtin_bit_cast(__half2, hv0.y);
      hp[2]  = __builtin_bit_cast(__half2, hv0.z);
      hp[3]  = __builtin_bit_cast(__half2, hv0.w);
      hp[4]  = __builtin_bit_cast(__half2, hv1.x);
      hp[5]  = __builtin_bit_cast(__half2, hv1.y);
      hp[6]  = __builtin_bit_cast(__half2, hv1.z);
      hp[7]  = __builtin_bit_cast(__half2, hv1.w);
      hp[8]  = __builtin_bit_cast(__half2, hv2.x);
      hp[9]  = __builtin_bit_cast(__half2, hv2.y);
      hp[10] = __builtin_bit_cast(__half2, hv2.z);
      hp[11] = __builtin_bit_cast(__half2, hv2.w);
      hp[12] = __builtin_bit_cast(__half2, hv3.x);
      hp[13] = __builtin_bit_cast(__half2, hv3.y);
      hp[14] = __builtin_bit_cast(__half2, hv3.z);
      hp[15] = __builtin_bit_cast(__half2, hv3.w);
      hp[16] = __builtin_bit_cast(__half2, hv4.x);
      hp[17] = __builtin_bit_cast(__half2, hv4.y);
      hp[18] = __builtin_bit_cast(__half2, hv4.z);
      hp[19] = __builtin_bit_cast(__half2, hv4.w);
      hp[20] = __builtin_bit_cast(__half2, hv5.x);
      hp[21] = __builtin_bit_cast(__half2, hv5.y);
      hp[22] = __builtin_bit_cast(__half2, hv5.z);
      hp[23] = __builtin_bit_cast(__half2, hv5.w);
      hp[24] = __builtin_bit_cast(__half2, hv6);

      // 4-gate partial dots over this lane's 50 k values
      float racc[4];
#if HAVE_FDOT2
#pragma unroll
      for (int g = 0; g < 4; g++) {
        float a0 = 0.f, a1 = 0.f;
#pragma unroll
        for (int q = 0; q < 25; q += 2)
          a0 = __builtin_amdgcn_fdot2(__builtin_bit_cast(h2, wp[g][q]),
                                      __builtin_bit_cast(h2, hp[q]), a0, false);
#pragma unroll
        for (int q = 1; q < 25; q += 2)
          a1 = __builtin_amdgcn_fdot2(__builtin_bit_cast(h2, wp[g][q]),
                                      __builtin_bit_cast(h2, hp[q]), a1, false);
        racc[g] = a0 + a1;
      }
#else
      __half2 z = __floats2half2_rn(0.f, 0.f);
#pragma unroll
      for (int g = 0; g < 4; g++) {
        __half2 a0 = z, a1 = z;
#pragma unroll
        for (int q = 0; q < 25; q += 2) a0 = __hfma2(wp[g][q], hp[q], a0);
#pragma unroll
        for (int q = 1; q < 25; q += 2) a1 = __hfma2(wp[g][q], hp[q], a1);
        racc[g] = (__low2float(a0) + __high2float(a0)) +
                  (__low2float(a1) + __high2float(a1));
      }
#endif

      // add pre (each lane of the pair contributes 2 gates), then pair-reduce
      if (kh == 0) { racc[0] += paF; racc[1] += pbF; }
      else         { racc[2] += paF; racc[3] += pbF; }
#pragma unroll
      for (int g = 0; g < 4; g++) racc[g] += __shfl_xor(racc[g], 1);

      // activations (both lanes of the pair compute identically; no divergence)
      float ig = sigm(racc[0]), fg = sigm(racc[1]);
      float g2 = tanh_fast(racc[2]), og = sigm(racc[3]);
      c = fg * c + ig * g2;
      float h = og * tanh_fast(c);

      if (act && kh == 0) {
        int seg = (j >= 50) ? 1 : 0;
        hsh[cur ^ 1][seg][j - seg * 50] = (_Float16)h;
        *hptr = (_Float16)h;
      }

      barrier_lds_only();
      cur ^= 1;
      preOff += pdelta;
      hptr += hstep;
    }
  }
#undef GSRC
}

// ---------------- K4: emission = [h_f,h_b] @ proj_w^T + proj_b (R25/R31 form — proven 470us run) ----------------
__global__ __launch_bounds__(256) void k_proj(const _Float16* __restrict__ hbuf,
                                              const float* __restrict__ pw,
                                              const float* __restrict__ pb,
                                              float* __restrict__ em) {
  __shared__ __align__(16) float pws[NTAGS * 204];   // 25.9 KB
  __shared__ float pbs[NTAGS];
  int tid = threadIdx.x;
  for (int i = tid; i < NTAGS * 2 * HDIM; i += 256) {
    int tag = i / (2 * HDIM);
    int k = i - tag * (2 * HDIM);
    pws[tag * 204 + k] = pw[i];
  }
  if (tid < NTAGS) pbs[tid] = pb[tid];
  __syncthreads();

  int idx = blockIdx.x * blockDim.x + tid;  // token*32 + tag
  if (idx >= BB * SS * NTAGS) return;
  int token = idx >> 5, tag = idx & 31;
  const uint4* h4 = (const uint4*)(hbuf + (size_t)token * 2 * HDIM);
  const float4* w4 = (const float4*)&pws[tag * 204];
  float acc = pbs[tag];
#pragma unroll
  for (int k = 0; k < 25; k++) {
    uint4 hv = h4[k];
    h2 a = __builtin_bit_cast(h2, hv.x);
    h2 bq = __builtin_bit_cast(h2, hv.y);
    h2 cq = __builtin_bit_cast(h2, hv.z);
    h2 d = __builtin_bit_cast(h2, hv.w);
    float4 w0 = w4[k * 2], w1 = w4[k * 2 + 1];
    acc += (float)a.x * w0.x + (float)a.y * w0.y + (float)bq.x * w0.z + (float)bq.y * w0.w
         + (float)cq.x * w1.x + (float)cq.y * w1.y + (float)d.x * w1.z + (float)d.y * w1.w;
  }
  em[idx] = acc;
}

// ---------------- K5: CRF forward + gold score + loss (R31 form — measured best; A/B closed) ----------------
// R33 A/B: R32's zero-cross-lane chain (+8 reads, 32-wide tree, +16 exps) is
// ~25us SLOWER than this 4-read + 2-shfl form. This is the measured optimum
// of three variants (R31 < R32 < R30-swizzle). Locked.
__global__ __launch_bounds__(64) void k_crf(const float* __restrict__ em,
                                            const float* __restrict__ trans,
                                            const int* __restrict__ mask,
                                            const int* __restrict__ y,
                                            float* __restrict__ out) {
  int b = blockIdx.x;
  int lane = threadIdx.x;
  int j = lane & 31;
  int h = lane >> 5;

  __shared__ __align__(16) float emS[SS * NTAGS];   // 32 KB
  __shared__ __align__(16) int mkS[SS];             // 1 KB
  __shared__ __align__(16) float laS[2][32];
  {
    const uint4* src = (const uint4*)(em + (size_t)b * SS * NTAGS);
#pragma unroll
    for (int p = 0; p < 32; p++) {
      uint4 t = src[p * 64 + lane];
      *(uint4*)&emS[(p * 64 + lane) * 4] = t;
    }
    uint4 mv = ((const uint4*)(mask + (size_t)b * SS))[lane];
    *(uint4*)&mkS[lane * 4] = mv;
  }
  barrier_lds_only();

  // ---- gold path score, 64 lanes (em from LDS) ----
  float sacc = 0.f;
  for (int s = lane; s < SS; s += 64) {
    int curt = y[b * SS + s];
    int prevt = (s == 0) ? TAG_START : y[b * SS + s - 1];
    float mk = (float)mkS[s];
    sacc += (emS[s * NTAGS + curt] + trans[prevt * NTAGS + curt]) * mk;
  }
#pragma unroll
  for (int off = 32; off > 0; off >>= 1) sacc += __shfl_down(sacc, off);
  float scoreYv = __shfl(sacc, 0) + trans[y[b * SS + SS - 1] * NTAGS + TAG_END];

  float tcol[16];
#pragma unroll
  for (int i = 0; i < 16; i++) tcol[i] = trans[(h * 16 + i) * NTAGS + j];

  float la = (j == TAG_START) ? 0.f : NEGV;

  for (int s = 0; s < SS; s++) {
    float e0 = emS[s * NTAGS + j];
    float mkv = (float)mkS[s];

    if (lane < 32) laS[s & 1][lane] = la;
    asm volatile("s_waitcnt lgkmcnt(0)" ::: "memory");
    const float4* lp = (const float4*)&laS[s & 1][h * 16];
    float4 t0 = lp[0], t1 = lp[1], t2 = lp[2], t3 = lp[3];

    float v[16];
    v[0] = t0.x + tcol[0];  v[1] = t0.y + tcol[1];
    v[2] = t0.z + tcol[2];  v[3] = t0.w + tcol[3];
    v[4] = t1.x + tcol[4];  v[5] = t1.y + tcol[5];
    v[6] = t1.z + tcol[6];  v[7] = t1.w + tcol[7];
    v[8] = t2.x + tcol[8];  v[9] = t2.y + tcol[9];
    v[10] = t2.z + tcol[10]; v[11] = t2.w + tcol[11];
    v[12] = t3.x + tcol[12]; v[13] = t3.y + tcol[13];
    v[14] = t3.z + tcol[14]; v[15] = t3.w + tcol[15];

    float ma = v[0], mb2 = v[1];
#pragma unroll
    for (int i = 2; i < 16; i += 2) { ma = fmaxf(ma, v[i]); mb2 = fmaxf(mb2, v[i + 1]); }
    float mh = fmaxf(ma, mb2);
    float m = fmaxf(mh, __shfl_xor(mh, 32));

    float sa = 0.f, sb = 0.f;
#pragma unroll
    for (int i = 0; i < 16; i += 2) { sa += __expf(v[i] - m); sb += __expf(v[i + 1] - m); }
    float sh = sa + sb;
    float sum = sh + __shfl_xor(sh, 32);

    float la2 = m + __logf(sum) + e0;
    la = la2 * mkv + la * (1.f - mkv);
  }
  la += trans[j * NTAGS + TAG_END];

  float mm = la;
#pragma unroll
  for (int off = 16; off > 0; off >>= 1) mm = fmaxf(mm, __shfl_xor(mm, off));
  float ss = __expf(la - mm);
#pragma unroll
  for (int off = 16; off > 0; off >>= 1) ss += __shfl_xor(ss, off);
  float total = mm + __logf(ss);
  if (lane == 0) atomicAdd(out, (total - scoreYv) * (1.0f / BB));
}

extern "C" void kernel_launch(void* const* d_in, const int* in_sizes, int n_in,
                              void* d_out, int out_size, void* d_ws, size_t ws_size,
                              hipStream_t stream) {
  const float* word_emb = (const float*)d_in[0];
  const float* char_emb = (const float*)d_in[1];
  const float* conv_w   = (const float*)d_in[2];
  const float* conv_b   = (const float*)d_in[3];
  const float* wih_f    = (const float*)d_in[4];
  const float* whh_f    = (const float*)d_in[5];
  const float* bih_f    = (const float*)d_in[6];
  const float* bhh_f    = (const float*)d_in[7];
  const float* wih_b    = (const float*)d_in[8];
  const float* whh_b    = (const float*)d_in[9];
  const float* bih_b    = (const float*)d_in[10];
  const float* bhh_b    = (const float*)d_in[11];
  const float* proj_w   = (const float*)d_in[12];
  const float* proj_b   = (const float*)d_in[13];
  const float* trans    = (const float*)d_in[14];
  const int* word_x     = (const int*)d_in[15];
  const int* char_x     = (const int*)d_in[16];
  const int* y          = (const int*)d_in[17];
  const int* mask       = (const int*)d_in[18];
  float* out = (float*)d_out;

  _Float16* x16   = (_Float16*)d_ws;                     // 32768*160 halves
  _Float16* w16   = x16 + (size_t)BB * SS * KPAD;        // 832*160 halves
  _Float16* preF  = w16 + (size_t)NROWS * KPAD;          // 32768*400 halves
  _Float16* preB  = preF + (size_t)BB * SS * GDIM;       // 32768*400 halves
  _Float16* hbuf  = preB + (size_t)BB * SS * GDIM;       // 32768*200 halves
  float* em       = (float*)(hbuf + (size_t)BB * SS * 2 * HDIM);  // 32768*32 f32

  k_pre<<<NB_PRE, 512, 0, stream>>>(word_emb, word_x, char_emb, conv_w, conv_b,
                                    char_x, wih_f, wih_b, x16, w16, out);
  k_pregemm<<<BB * SS / 64, 256, 0, stream>>>(x16, w16, bih_f, bhh_f,
                                              bih_b, bhh_b, preF, preB);
  k_lstm<<<256, 256, 0, stream>>>(preF, preB, whh_f, whh_b, hbuf);
  k_proj<<<(BB * SS * NTAGS + 255) / 256, 256, 0, stream>>>(hbuf, proj_w, proj_b, em);
  k_crf<<<BB, 64, 0, stream>>>(em, trans, mask, y, out);
}

// Round 18
// 439.190 us; speedup vs baseline: 1.2245x; 1.0649x over previous
//
#include <hip/hip_runtime.h>
#include <hip/hip_fp16.h>
#include <cstdint>
#include <cstddef>

#define BB 128
#define SS 256
#define LL 10
#define NTAGS 32
#define TAG_START 30
#define TAG_END 31
#define WDIM 100
#define CDIM 30
#define NFILT 30
#define HDIM 100
#define KIN 130      // LSTM_IN = WDIM + FILT
#define KPAD 160     // padded K for f16 GEMM operands
#define GDIM 400     // 4*H
#define NROWS 832    // 13*64 padded W rows
#define NEGV -10000.0f
#define CTOK 16      // tokens per charconv block (R34)

// fused-pre block ranges (R34: 512-thread blocks)
#define NB_CONV (BB * SS / CTOK)               // 2048
#define NB_WORDA (BB * SS * 12 / 512)          // 768
#define NB_WORDB (BB * SS * 20 / 512)          // 1280
#define NB_WCVT (NROWS * KPAD / 512)           // 260
#define NB_PRE  (NB_CONV + NB_WORDA + NB_WORDB + NB_WCVT)  // 4356

typedef _Float16 h2 __attribute__((ext_vector_type(2)));
typedef _Float16 f16x8 __attribute__((ext_vector_type(8)));
typedef float f32x4 __attribute__((ext_vector_type(4)));

#if __has_builtin(__builtin_amdgcn_fdot2)
#define HAVE_FDOT2 1
#else
#define HAVE_FDOT2 0
#endif

__device__ __forceinline__ float sigm(float x) { return 1.0f / (1.0f + __expf(-x)); }
__device__ __forceinline__ float tanh_fast(float x) { return 2.0f / (1.0f + __expf(-2.0f * x)) - 1.0f; }

// lgkm-only barrier (R15-proven): leaves global prefetch/store in flight.
__device__ __forceinline__ void barrier_lds_only() {
  asm volatile("s_waitcnt lgkmcnt(0)" ::: "memory");
  __builtin_amdgcn_s_barrier();
  asm volatile("" ::: "memory");
}

// ---------------- K1 fused: charconv | word gather | wcvt, by block range ----------------
__global__ __launch_bounds__(512) void k_pre(
    const float* __restrict__ wemb, const int* __restrict__ wx,
    const float* __restrict__ cemb, const float* __restrict__ convw,
    const float* __restrict__ convb, const int* __restrict__ cx,
    const float* __restrict__ wihF, const float* __restrict__ wihB,
    _Float16* __restrict__ x16, _Float16* __restrict__ w16,
    float* __restrict__ out) {
  int blk = blockIdx.x;
  int tid = threadIdx.x;
  if (blk == 0 && tid == 0) out[0] = 0.f;

  if (blk < NB_CONV) {
    int tok = tid >> 5;                  // 0..15
    int f = tid & 31;
    int token0 = blk * CTOK;
    __shared__ float e[CTOK][LL * CDIM];              // 19.2 KB
    __shared__ float cw[NFILT * 3 * CDIM];            // 10.8 KB
    __shared__ float cb[NFILT];
    __shared__ int ci[CTOK][LL];
    if (tid < CTOK * LL) {
      int t = tid / LL, l = tid - t * LL;
      ci[t][l] = cx[(token0 + t) * LL + l];
    }
    for (int i = tid; i < NFILT * 3 * CDIM; i += 512) cw[i] = convw[i];
    if (tid < NFILT) cb[tid] = convb[tid];
    __syncthreads();
    for (int i = tid; i < CTOK * LL * CDIM; i += 512) {
      int t = i / (LL * CDIM);
      int r = i - t * (LL * CDIM);
      int l = r / CDIM, c = r - l * CDIM;
      e[t][l * CDIM + c] = cemb[ci[t][l] * CDIM + c];
    }
    __syncthreads();
    if (f < NFILT) {
      float d0[LL], d1[LL], d2[LL];
#pragma unroll
      for (int l = 0; l < LL; l++) { d0[l] = 0.f; d1[l] = 0.f; d2[l] = 0.f; }
      const float* et = &e[tok][0];
      for (int c = 0; c < CDIM; c++) {
        float w0 = cw[(f * 3 + 0) * CDIM + c];
        float w1 = cw[(f * 3 + 1) * CDIM + c];
        float w2 = cw[(f * 3 + 2) * CDIM + c];
#pragma unroll
        for (int l = 0; l < LL; l++) {
          float ev = et[l * CDIM + c];
          d0[l] += ev * w0; d1[l] += ev * w1; d2[l] += ev * w2;
        }
      }
      float bias = cb[f];
      float m = -3.0e38f;
#pragma unroll
      for (int h = 0; h < LL + 2; h++) {
        float acc = bias;
        int j0 = h - 2, j1 = h - 1, j2 = h;
        if (j0 >= 0 && j0 < LL) acc += d0[j0];
        if (j1 >= 0 && j1 < LL) acc += d1[j1];
        if (j2 >= 0 && j2 < LL) acc += d2[j2];
        m = fmaxf(m, acc);
      }
      x16[(size_t)(token0 + tok) * KPAD + WDIM + f] = (_Float16)m;
    }
  } else if (blk < NB_CONV + NB_WORDA) {
    // vectorized word gather: one uint4 (8 halves) per thread, d in [0,96)
    int idx = (blk - NB_CONV) * 512 + tid;
    int token = idx / 12;
    int g = idx - token * 12;
    const float* src = wemb + (size_t)wx[token] * WDIM + g * 8;
    float4 f0 = *(const float4*)(src);
    float4 f1 = *(const float4*)(src + 4);
    f16x8 v;
    v[0] = (_Float16)f0.x; v[1] = (_Float16)f0.y;
    v[2] = (_Float16)f0.z; v[3] = (_Float16)f0.w;
    v[4] = (_Float16)f1.x; v[5] = (_Float16)f1.y;
    v[6] = (_Float16)f1.z; v[7] = (_Float16)f1.w;
    *(f16x8*)&x16[(size_t)token * KPAD + g * 8] = v;
  } else if (blk < NB_CONV + NB_WORDA + NB_WORDB) {
    // tail: d 96..99 scalar wemb; zeros for d in [130,160) as uint pairs
    int idx = (blk - NB_CONV - NB_WORDA) * 512 + tid;
    int token = idx / 20;
    int u = idx - token * 20;
    if (u < 4) {
      x16[(size_t)token * KPAD + 96 + u] = (_Float16)wemb[(size_t)wx[token] * WDIM + 96 + u];
    } else if (u < 19) {
      *(uint32_t*)&x16[(size_t)token * KPAD + KIN + 2 * (u - 4)] = 0;
    }
  } else {
    int idx = (blk - NB_CONV - NB_WORDA - NB_WORDB) * 512 + tid;
    int n = idx / KPAD;
    int k = idx - n * KPAD;
    float v = 0.f;
    if (k < KIN && n < 2 * GDIM) {
      v = (n < GDIM) ? wihF[(size_t)n * KIN + k] : wihB[(size_t)(n - GDIM) * KIN + k];
    }
    w16[idx] = (_Float16)v;
  }
}

// ---------------- K2: pre = x @ wih^T + (bih+bhh), MFMA f16 (R25: n-loop-in-block) ----------------
__global__ __launch_bounds__(256) void k_pregemm(
    const _Float16* __restrict__ x16, const _Float16* __restrict__ w16,
    const float* __restrict__ bihF, const float* __restrict__ bhhF,
    const float* __restrict__ bihB, const float* __restrict__ bhhB,
    _Float16* __restrict__ preF, _Float16* __restrict__ preB) {
  __shared__ __align__(16) _Float16 Asl[64 * 168];      // 21.5 KB
  __shared__ __align__(16) _Float16 Bsl[2][64 * 168];   // 43 KB
  int m0 = blockIdx.x * 64;
  int tid = threadIdx.x;
  int lane = tid & 63, w = tid >> 6;
  int quad = lane >> 4, l15 = lane & 15;
  int r = tid >> 2;            // staging row 0..63
  int kk = (tid & 3) * 8;      // k offset within chunk

  const _Float16* xs = x16 + (size_t)(m0 + r) * KPAD + kk;
  const _Float16* ws = w16 + (size_t)r * KPAD + kk;
#pragma unroll
  for (int kc = 0; kc < 5; kc++) {
    *(f16x8*)&Asl[r * 168 + kc * 32 + kk] = *(const f16x8*)(xs + kc * 32);
    *(f16x8*)&Bsl[0][r * 168 + kc * 32 + kk] = *(const f16x8*)(ws + kc * 32);
  }
  __syncthreads();

  for (int nt = 0; nt < 13; nt++) {
    int cur = nt & 1;
    // prefetch next B tile into registers (stays in flight across compute)
    f16x8 nb0, nb1, nb2, nb3, nb4;
    if (nt + 1 < 13) {
      const _Float16* wn = w16 + (size_t)((nt + 1) * 64 + r) * KPAD + kk;
      nb0 = *(const f16x8*)(wn);
      nb1 = *(const f16x8*)(wn + 32);
      nb2 = *(const f16x8*)(wn + 64);
      nb3 = *(const f16x8*)(wn + 96);
      nb4 = *(const f16x8*)(wn + 128);
    }

    f32x4 acc[4];
#pragma unroll
    for (int i = 0; i < 4; i++) acc[i] = (f32x4){0.f, 0.f, 0.f, 0.f};
#pragma unroll
    for (int kc = 0; kc < 5; kc++) {
      f16x8 bfrag = *(const f16x8*)&Bsl[cur][(w * 16 + l15) * 168 + kc * 32 + quad * 8];
#pragma unroll
      for (int mt = 0; mt < 4; mt++) {
        f16x8 afrag = *(const f16x8*)&Asl[(mt * 16 + l15) * 168 + kc * 32 + quad * 8];
        acc[mt] = __builtin_amdgcn_mfma_f32_16x16x32_f16(afrag, bfrag, acc[mt], 0, 0, 0);
      }
    }

    int ng = nt * 64 + w * 16 + l15;  // this lane's output column
    if (ng < 2 * GDIM) {
      int dir = ng >= GDIM;
      int jb = dir ? ng - GDIM : ng;
      _Float16* dst = dir ? preB : preF;
      float bias = (dir ? bihB : bihF)[jb] + (dir ? bhhB : bhhF)[jb];
#pragma unroll
      for (int mt = 0; mt < 4; mt++) {
#pragma unroll
        for (int i = 0; i < 4; i++) {
          int m = m0 + mt * 16 + quad * 4 + i;
          dst[(size_t)m * GDIM + jb] = (_Float16)(acc[mt][i] + bias);
        }
      }
    }

    if (nt + 1 < 13) {
      asm volatile("s_waitcnt vmcnt(0)" ::: "memory");
      int nxt = cur ^ 1;   // buffer last READ in iteration nt-1; all waves past
      *(f16x8*)&Bsl[nxt][r * 168 + 0 * 32 + kk] = nb0;
      *(f16x8*)&Bsl[nxt][r * 168 + 1 * 32 + kk] = nb1;
      *(f16x8*)&Bsl[nxt][r * 168 + 2 * 32 + kk] = nb2;
      *(f16x8*)&Bsl[nxt][r * 168 + 3 * 32 + kk] = nb3;
      *(f16x8*)&Bsl[nxt][r * 168 + 4 * 32 + kk] = nb4;
      __syncthreads();
    }
  }
}

// ---------------- K3: recurrent LSTM scan (R21 fdot2 structure, best measured 164us) ----------------
#define CH 32
#define NCH (SS / CH)
__global__ __launch_bounds__(256, 1) void k_lstm(
    const _Float16* __restrict__ preF, const _Float16* __restrict__ preB,
    const float* __restrict__ whhF, const float* __restrict__ whhB,
    _Float16* __restrict__ hbuf) {
  int blk = blockIdx.x;              // 256 blocks
  int dir = blk >> 7;                // 0 fwd, 1 bwd
  int b = blk & 127;
  const _Float16* pre = dir ? preB : preF;
  const float* whh = dir ? whhB : whhF;
  int tid = threadIdx.x;
  int j = tid >> 1;                  // cell 0..127 (valid < 100)
  int kh = tid & 1;                  // k-half: [0,50) or [50,100)
  bool act = (j < HDIM);
  int jc = act ? j : 0;

  // ---- weight preload: wp[g][q] = whh[g*100+j][kh*50 + 2q .. +1] as half2 ----
  __half2 wp[4][25];
#pragma unroll
  for (int g = 0; g < 4; g++) {
    const float* wr = whh + (size_t)(g * HDIM + jc) * HDIM + kh * 50;
#pragma unroll
    for (int q = 0; q < 25; q++) {
      wp[g][q] = __floats2half2_rn(wr[2 * q], wr[2 * q + 1]);
    }
  }

  // ---- LDS: pre chunk buffer (28.7 KB) + h double buffer (512 B) ----
  __shared__ __align__(16) _Float16 preS[14336];   // 1792 uint4
  __shared__ __align__(16) _Float16 hsh[2][2][64];
  if (tid < 128) ((int*)hsh)[tid] = 0;
  float c = 0.f;

#define GSRC(ck) ((const uint4*)(pre + ((size_t)b * SS + (dir ? (SS - CH - (ck) * CH) : ((ck) * CH))) * GDIM))

  uint4 r0, r1, r2, r3, r4, r5, r6;
  {
    const uint4* s0 = GSRC(0);
    r0 = s0[0 * 256 + tid]; r1 = s0[1 * 256 + tid]; r2 = s0[2 * 256 + tid];
    r3 = s0[3 * 256 + tid]; r4 = s0[4 * 256 + tid]; r5 = s0[5 * 256 + tid];
    r6 = s0[6 * 256 + tid];
  }

  _Float16* hptr = hbuf + ((size_t)b * SS + (dir ? (SS - 1) : 0)) * (2 * HDIM) + dir * HDIM + jc;
  const intptr_t hstep = dir ? -(intptr_t)(2 * HDIM) : (intptr_t)(2 * HDIM);

  int cur = 0;
  for (int ck = 0; ck < NCH; ck++) {
    asm volatile("s_waitcnt vmcnt(0)" ::: "memory");   // staged regs landed
    *(uint4*)&preS[(0 * 256 + tid) * 8] = r0;
    *(uint4*)&preS[(1 * 256 + tid) * 8] = r1;
    *(uint4*)&preS[(2 * 256 + tid) * 8] = r2;
    *(uint4*)&preS[(3 * 256 + tid) * 8] = r3;
    *(uint4*)&preS[(4 * 256 + tid) * 8] = r4;
    *(uint4*)&preS[(5 * 256 + tid) * 8] = r5;
    *(uint4*)&preS[(6 * 256 + tid) * 8] = r6;
    if (ck + 1 < NCH) {
      const uint4* snx = GSRC(ck + 1);
      r0 = snx[0 * 256 + tid]; r1 = snx[1 * 256 + tid]; r2 = snx[2 * 256 + tid];
      r3 = snx[3 * 256 + tid]; r4 = snx[4 * 256 + tid]; r5 = snx[5 * 256 + tid];
      r6 = snx[6 * 256 + tid];
    }
    barrier_lds_only();   // preS (and hsh zeros on ck=0) visible to all waves

    int preOff = (dir ? (CH - 1) * GDIM : 0) + kh * 200 + jc;
    const int pdelta = dir ? -GDIM : GDIM;

    for (int s2 = 0; s2 < CH; s2++) {
      float paF = (float)preS[preOff];
      float pbF = (float)preS[preOff + 100];

      // h of previous step: 50 halves of this lane's k-half (broadcast reads)
      const _Float16* hseg = &hsh[cur][kh][0];
      uint4 hv0 = *(const uint4*)(hseg);
      uint4 hv1 = *(const uint4*)(hseg + 8);
      uint4 hv2 = *(const uint4*)(hseg + 16);
      uint4 hv3 = *(const uint4*)(hseg + 24);
      uint4 hv4 = *(const uint4*)(hseg + 32);
      uint4 hv5 = *(const uint4*)(hseg + 40);
      uint32_t hv6 = *(const uint32_t*)(hseg + 48);
      __half2 hp[25];
      hp[0]  = __builtin_bit_cast(__half2, hv0.x);
      hp[1]  = __builtin_bit_cast(__half2, hv0.y);
      hp[2]  = __builtin_bit_cast(__half2, hv0.z);
      hp[3]  = __builtin_bit_cast(__half2, hv0.w);
      hp[4]  = __builtin_bit_cast(__half2, hv1.x);
      hp[5]  = __builtin_bit_cast(__half2, hv1.y);
      hp[6]  = __builtin_bit_cast(__half2, hv1.z);
      hp[7]  = __builtin_bit_cast(__half2, hv1.w);
      hp[8]  = __builtin_bit_cast(__half2, hv2.x);
      hp[9]  = __builtin_bit_cast(__half2, hv2.y);
      hp[10] = __builtin_bit_cast(__half2, hv2.z);
      hp[11] = __builtin_bit_cast(__half2, hv2.w);
      hp[12] = __builtin_bit_cast(__half2, hv3.x);
      hp[13] = __builtin_bit_cast(__half2, hv3.y);
      hp[14] = __builtin_bit_cast(__half2, hv3.z);
      hp[15] = __builtin_bit_cast(__half2, hv3.w);
      hp[16] = __builtin_bit_cast(__half2, hv4.x);
      hp[17] = __builtin_bit_cast(__half2, hv4.y);
      hp[18] = __builtin_bit_cast(__half2, hv4.z);
      hp[19] = __builtin_bit_cast(__half2, hv4.w);
      hp[20] = __builtin_bit_cast(__half2, hv5.x);
      hp[21] = __builtin_bit_cast(__half2, hv5.y);
      hp[22] = __builtin_bit_cast(__half2, hv5.z);
      hp[23] = __builtin_bit_cast(__half2, hv5.w);
      hp[24] = __builtin_bit_cast(__half2, hv6);

      // 4-gate partial dots over this lane's 50 k values
      float racc[4];
#if HAVE_FDOT2
#pragma unroll
      for (int g = 0; g < 4; g++) {
        float a0 = 0.f, a1 = 0.f;
#pragma unroll
        for (int q = 0; q < 25; q += 2)
          a0 = __builtin_amdgcn_fdot2(__builtin_bit_cast(h2, wp[g][q]),
                                      __builtin_bit_cast(h2, hp[q]), a0, false);
#pragma unroll
        for (int q = 1; q < 25; q += 2)
          a1 = __builtin_amdgcn_fdot2(__builtin_bit_cast(h2, wp[g][q]),
                                      __builtin_bit_cast(h2, hp[q]), a1, false);
        racc[g] = a0 + a1;
      }
#else
      __half2 z = __floats2half2_rn(0.f, 0.f);
#pragma unroll
      for (int g = 0; g < 4; g++) {
        __half2 a0 = z, a1 = z;
#pragma unroll
        for (int q = 0; q < 25; q += 2) a0 = __hfma2(wp[g][q], hp[q], a0);
#pragma unroll
        for (int q = 1; q < 25; q += 2) a1 = __hfma2(wp[g][q], hp[q], a1);
        racc[g] = (__low2float(a0) + __high2float(a0)) +
                  (__low2float(a1) + __high2float(a1));
      }
#endif

      // add pre (each lane of the pair contributes 2 gates), then pair-reduce
      if (kh == 0) { racc[0] += paF; racc[1] += pbF; }
      else         { racc[2] += paF; racc[3] += pbF; }
#pragma unroll
      for (int g = 0; g < 4; g++) racc[g] += __shfl_xor(racc[g], 1);

      // activations (both lanes of the pair compute identically; no divergence)
      float ig = sigm(racc[0]), fg = sigm(racc[1]);
      float g2 = tanh_fast(racc[2]), og = sigm(racc[3]);
      c = fg * c + ig * g2;
      float h = og * tanh_fast(c);

      if (act && kh == 0) {
        int seg = (j >= 50) ? 1 : 0;
        hsh[cur ^ 1][seg][j - seg * 50] = (_Float16)h;
        *hptr = (_Float16)h;
      }

      barrier_lds_only();
      cur ^= 1;
      preOff += pdelta;
      hptr += hstep;
    }
  }
#undef GSRC
}

// ---------------- K4: emission = [h_f,h_b] @ proj_w^T + proj_b (R25/R31 form) ----------------
__global__ __launch_bounds__(256) void k_proj(const _Float16* __restrict__ hbuf,
                                              const float* __restrict__ pw,
                                              const float* __restrict__ pb,
                                              float* __restrict__ em) {
  __shared__ __align__(16) float pws[NTAGS * 204];   // 25.9 KB
  __shared__ float pbs[NTAGS];
  int tid = threadIdx.x;
  for (int i = tid; i < NTAGS * 2 * HDIM; i += 256) {
    int tag = i / (2 * HDIM);
    int k = i - tag * (2 * HDIM);
    pws[tag * 204 + k] = pw[i];
  }
  if (tid < NTAGS) pbs[tid] = pb[tid];
  __syncthreads();

  int idx = blockIdx.x * blockDim.x + tid;  // token*32 + tag
  if (idx >= BB * SS * NTAGS) return;
  int token = idx >> 5, tag = idx & 31;
  const uint4* h4 = (const uint4*)(hbuf + (size_t)token * 2 * HDIM);
  const float4* w4 = (const float4*)&pws[tag * 204];
  float acc = pbs[tag];
#pragma unroll
  for (int k = 0; k < 25; k++) {
    uint4 hv = h4[k];
    h2 a = __builtin_bit_cast(h2, hv.x);
    h2 bq = __builtin_bit_cast(h2, hv.y);
    h2 cq = __builtin_bit_cast(h2, hv.z);
    h2 d = __builtin_bit_cast(h2, hv.w);
    float4 w0 = w4[k * 2], w1 = w4[k * 2 + 1];
    acc += (float)a.x * w0.x + (float)a.y * w0.y + (float)bq.x * w0.z + (float)bq.y * w0.w
         + (float)cq.x * w1.x + (float)cq.y * w1.y + (float)d.x * w1.z + (float)d.y * w1.w;
  }
  em[idx] = acc;
}

// ---------------- K5: CRF — factored-exp step chain (R35) ----------------
// la2_j = M + log(sum_i exp(la_i - M) * E_ij) + e_j with E_ij = exp(T_ij)
// precomputed (T clamped at -45 so sums never denormal-flush to 0). Deletes
// the per-step max tree + BOTH shfl_xor(32)s (~260cy, R30/R32-quantified) and
// 15 of 16 exps; chain = 1 exp + write + lgkm + reads + 32 fma + log. M kept
// uniform with zero extra latency: lane0 stores la each step into slot 32,
// read two-steps-stale under the same lgkm wait (staleness bound ~35 ->
// u <= e^50, f32-safe; slots pre-zeroed so steps 0/1 use M=0, exactly right
// for the one-hot init). Mask blend = exact select (mask is 0/1).
__global__ __launch_bounds__(64) void k_crf(const float* __restrict__ em,
                                            const float* __restrict__ trans,
                                            const int* __restrict__ mask,
                                            const int* __restrict__ y,
                                            float* __restrict__ out) {
  int b = blockIdx.x;
  int lane = threadIdx.x;
  int j = lane & 31;

  __shared__ __align__(16) float emS[SS * NTAGS];   // 32 KB
  __shared__ __align__(16) int mkS[SS];             // 1 KB
  __shared__ __align__(16) float laS[2][36];        // [buf][0..31]=u, [32]=M slot
  {
    const uint4* src = (const uint4*)(em + (size_t)b * SS * NTAGS);
#pragma unroll
    for (int p = 0; p < 32; p++) {
      uint4 t = src[p * 64 + lane];
      *(uint4*)&emS[(p * 64 + lane) * 4] = t;
    }
    uint4 mv = ((const uint4*)(mask + (size_t)b * SS))[lane];
    *(uint4*)&mkS[lane * 4] = mv;
    if (lane == 0) { laS[0][32] = 0.f; laS[1][32] = 0.f; }
  }
  barrier_lds_only();

  // ---- gold path score, 64 lanes (em from LDS) ----
  float sacc = 0.f;
  for (int s = lane; s < SS; s += 64) {
    int curt = y[b * SS + s];
    int prevt = (s == 0) ? TAG_START : y[b * SS + s - 1];
    float mk = (float)mkS[s];
    sacc += (emS[s * NTAGS + curt] + trans[prevt * NTAGS + curt]) * mk;
  }
#pragma unroll
  for (int off = 32; off > 0; off >>= 1) sacc += __shfl_down(sacc, off);
  float scoreYv = __shfl(sacc, 0) + trans[y[b * SS + SS - 1] * NTAGS + TAG_END];

  // ---- E table: E[i] = exp(clamp(T[i][j], -45)), 32 const VGPRs ----
  float E[32];
#pragma unroll
  for (int i = 0; i < 32; i++) E[i] = __expf(fmaxf(trans[i * NTAGS + j], -45.f));

  float la = (j == TAG_START) ? 0.f : NEGV;
  float M = 0.f;       // stabilizer for current step (two-step-stale la_0)

  for (int s = 0; s < SS; s++) {
    float e0 = emS[s * NTAGS + j];
    int mkv = mkS[s];

    float u = __expf(la - M);
    if (lane < 32) laS[s & 1][lane] = u;
    asm volatile("s_waitcnt lgkmcnt(0)" ::: "memory");
    const float4* lp = (const float4*)&laS[s & 1][0];
    float4 t0 = lp[0], t1 = lp[1], t2 = lp[2], t3 = lp[3];
    float4 t4 = lp[4], t5 = lp[5], t6 = lp[6], t7 = lp[7];
    float Mnext = laS[(s & 1) ^ 1][32];   // la_0 written at end of step s-1

    // sum_j = sum_i u_i * E_ij : 32 f32 fma, 4 independent chains
    float a0 = t0.x * E[0],  a1 = t0.y * E[1],  a2 = t0.z * E[2],  a3 = t0.w * E[3];
    a0 += t1.x * E[4];  a1 += t1.y * E[5];  a2 += t1.z * E[6];  a3 += t1.w * E[7];
    a0 += t2.x * E[8];  a1 += t2.y * E[9];  a2 += t2.z * E[10]; a3 += t2.w * E[11];
    a0 += t3.x * E[12]; a1 += t3.y * E[13]; a2 += t3.z * E[14]; a3 += t3.w * E[15];
    a0 += t4.x * E[16]; a1 += t4.y * E[17]; a2 += t4.z * E[18]; a3 += t4.w * E[19];
    a0 += t5.x * E[20]; a1 += t5.y * E[21]; a2 += t5.z * E[22]; a3 += t5.w * E[23];
    a0 += t6.x * E[24]; a1 += t6.y * E[25]; a2 += t6.z * E[26]; a3 += t6.w * E[27];
    a0 += t7.x * E[28]; a1 += t7.y * E[29]; a2 += t7.z * E[30]; a3 += t7.w * E[31];
    float sum = (a0 + a1) + (a2 + a3);

    float la2 = M + __logf(sum) + e0;
    la = mkv ? la2 : la;               // exact select (mask in {0,1})

    if (lane == 0) laS[s & 1][32] = la;  // this step's la_0 -> M two steps on
    M = Mnext;
  }
  la += trans[j * NTAGS + TAG_END];

  // ---- final logsumexp over j (lanes 32-63 duplicate lanes 0-31) ----
  float mm = la;
#pragma unroll
  for (int off = 16; off > 0; off >>= 1) mm = fmaxf(mm, __shfl_xor(mm, off));
  float ss = __expf(la - mm);
#pragma unroll
  for (int off = 16; off > 0; off >>= 1) ss += __shfl_xor(ss, off);
  float total = mm + __logf(ss);
  if (lane == 0) atomicAdd(out, (total - scoreYv) * (1.0f / BB));
}

extern "C" void kernel_launch(void* const* d_in, const int* in_sizes, int n_in,
                              void* d_out, int out_size, void* d_ws, size_t ws_size,
                              hipStream_t stream) {
  const float* word_emb = (const float*)d_in[0];
  const float* char_emb = (const float*)d_in[1];
  const float* conv_w   = (const float*)d_in[2];
  const float* conv_b   = (const float*)d_in[3];
  const float* wih_f    = (const float*)d_in[4];
  const float* whh_f    = (const float*)d_in[5];
  const float* bih_f    = (const float*)d_in[6];
  const float* bhh_f    = (const float*)d_in[7];
  const float* wih_b    = (const float*)d_in[8];
  const float* whh_b    = (const float*)d_in[9];
  const float* bih_b    = (const float*)d_in[10];
  const float* bhh_b    = (const float*)d_in[11];
  const float* proj_w   = (const float*)d_in[12];
  const float* proj_b   = (const float*)d_in[13];
  const float* trans    = (const float*)d_in[14];
  const int* word_x     = (const int*)d_in[15];
  const int* char_x     = (const int*)d_in[16];
  const int* y          = (const int*)d_in[17];
  const int* mask       = (const int*)d_in[18];
  float* out = (float*)d_out;

  _Float16* x16   = (_Float16*)d_ws;                     // 32768*160 halves
  _Float16* w16   = x16 + (size_t)BB * SS * KPAD;        // 832*160 halves
  _Float16* preF  = w16 + (size_t)NROWS * KPAD;          // 32768*400 halves
  _Float16* preB  = preF + (size_t)BB * SS * GDIM;       // 32768*400 halves
  _Float16* hbuf  = preB + (size_t)BB * SS * GDIM;       // 32768*200 halves
  float* em       = (float*)(hbuf + (size_t)BB * SS * 2 * HDIM);  // 32768*32 f32

  k_pre<<<NB_PRE, 512, 0, stream>>>(word_emb, word_x, char_emb, conv_w, conv_b,
                                    char_x, wih_f, wih_b, x16, w16, out);
  k_pregemm<<<BB * SS / 64, 256, 0, stream>>>(x16, w16, bih_f, bhh_f,
                                              bih_b, bhh_b, preF, preB);
  k_lstm<<<256, 256, 0, stream>>>(preF, preB, whh_f, whh_b, hbuf);
  k_proj<<<(BB * SS * NTAGS + 255) / 256, 256, 0, stream>>>(hbuf, proj_w, proj_b, em);
  k_crf<<<BB, 64, 0, stream>>>(em, trans, mask, y, out);
}